// Round 3
// baseline (835.423 us; speedup 1.0000x reference)
//
#include <hip/hip_runtime.h>
#include <math.h>

#define NT 1024
#define CD 2
#define DD 1024
#define GG 16
#define LOG1E6 -13.8155105579642740f
#define NEG_BIG -1e30f

// ---------------------------------------------------------------------------
// K1: fp32 GEMM  P_z[r][e] = sum_d A[r][d] * W_z[e][d] + b_z[e]
//     tile 128 rows x 64 cols, BK=32, 256 threads, 8x4 micro-tile
// ---------------------------------------------------------------------------
__global__ __launch_bounds__(256) void k1_proj(
    const float* __restrict__ fa,
    const float* __restrict__ Wq, const float* __restrict__ bq,
    const float* __restrict__ Wk, const float* __restrict__ bk,
    const float* __restrict__ Wc, const float* __restrict__ bc,
    float* __restrict__ Qo, float* __restrict__ Ko, float* __restrict__ Vo)
{
    const int et = blockIdx.x, rt = blockIdx.y, z = blockIdx.z;
    const float* W  = (z == 0) ? Wq : (z == 1) ? Wk : Wc;
    const float* bb = (z == 0) ? bq : (z == 1) ? bk : bc;
    float* Out      = (z == 0) ? Qo : (z == 1) ? Ko : Vo;

    __shared__ float Al[32][132];
    __shared__ float Wl[32][68];

    const int t  = threadIdx.x;
    const int tx = t & 15, ty = t >> 4;
    const int dd = t & 7,  rr = t >> 3;
    const int r0 = rt * 128, e0 = et * 64;

    float acc[8][4];
    #pragma unroll
    for (int a = 0; a < 8; ++a)
        #pragma unroll
        for (int b = 0; b < 4; ++b) acc[a][b] = 0.f;

    for (int kt = 0; kt < 32; ++kt) {
        const int db = kt * 32 + dd * 4;
        #pragma unroll
        for (int p = 0; p < 4; ++p) {
            const int row = rr + p * 32;
            const int r = r0 + row;
            const int n = r & (NT - 1), c = r >> 10;
            float4 a4 = *(const float4*)&fa[((size_t)(n * CD + c)) * DD + db];
            Al[dd*4+0][row] = a4.x; Al[dd*4+1][row] = a4.y;
            Al[dd*4+2][row] = a4.z; Al[dd*4+3][row] = a4.w;
        }
        #pragma unroll
        for (int p = 0; p < 2; ++p) {
            const int erow = rr + p * 32;
            float4 w4 = *(const float4*)&W[((size_t)(e0 + erow)) * DD + db];
            Wl[dd*4+0][erow] = w4.x; Wl[dd*4+1][erow] = w4.y;
            Wl[dd*4+2][erow] = w4.z; Wl[dd*4+3][erow] = w4.w;
        }
        __syncthreads();
        #pragma unroll 4
        for (int d = 0; d < 32; ++d) {
            float4 a0 = *(const float4*)&Al[d][ty * 8];
            float4 a1 = *(const float4*)&Al[d][ty * 8 + 4];
            float4 w4 = *(const float4*)&Wl[d][tx * 4];
            float av[8] = {a0.x, a0.y, a0.z, a0.w, a1.x, a1.y, a1.z, a1.w};
            float wv[4] = {w4.x, w4.y, w4.z, w4.w};
            #pragma unroll
            for (int a = 0; a < 8; ++a)
                #pragma unroll
                for (int b = 0; b < 4; ++b) acc[a][b] += av[a] * wv[b];
        }
        __syncthreads();
    }
    float4 b4 = *(const float4*)&bb[e0 + tx * 4];
    #pragma unroll
    for (int a = 0; a < 8; ++a) {
        float4 o;
        o.x = acc[a][0] + b4.x; o.y = acc[a][1] + b4.y;
        o.z = acc[a][2] + b4.z; o.w = acc[a][3] + b4.w;
        *(float4*)&Out[((size_t)(r0 + ty * 8 + a)) * DD + e0 + tx * 4] = o;
    }
}

// ---------------------------------------------------------------------------
// K2a: aff[c][g][i][j] = (sum_d Q[c,i,g*64+d] * K[c,j,g*64+d]) / 8
// ---------------------------------------------------------------------------
__global__ __launch_bounds__(256) void k2a_aff(
    const float* __restrict__ Q, const float* __restrict__ Km,
    float* __restrict__ aff)
{
    const int jt = blockIdx.x, it = blockIdx.y, cg = blockIdx.z;
    const int c = cg >> 4, g = cg & 15;
    __shared__ float Ql[64][68];
    __shared__ float Kl[64][68];
    const int t = threadIdx.x;
    const int dd = t & 15, rr = t >> 4;
    const int i0 = it * 64, j0 = jt * 64;
    #pragma unroll
    for (int p = 0; p < 4; ++p) {
        const int row = rr + p * 16;
        float4 q4 = *(const float4*)&Q[((size_t)(c * NT + i0 + row)) * DD + g * 64 + dd * 4];
        Ql[dd*4+0][row] = q4.x; Ql[dd*4+1][row] = q4.y;
        Ql[dd*4+2][row] = q4.z; Ql[dd*4+3][row] = q4.w;
        float4 k4 = *(const float4*)&Km[((size_t)(c * NT + j0 + row)) * DD + g * 64 + dd * 4];
        Kl[dd*4+0][row] = k4.x; Kl[dd*4+1][row] = k4.y;
        Kl[dd*4+2][row] = k4.z; Kl[dd*4+3][row] = k4.w;
    }
    __syncthreads();
    const int tx = t & 15, ty = t >> 4;
    float acc[4][4];
    #pragma unroll
    for (int a = 0; a < 4; ++a)
        #pragma unroll
        for (int b = 0; b < 4; ++b) acc[a][b] = 0.f;
    #pragma unroll 8
    for (int d = 0; d < 64; ++d) {
        float4 q4 = *(const float4*)&Ql[d][ty * 4];
        float4 k4 = *(const float4*)&Kl[d][tx * 4];
        float qv[4] = {q4.x, q4.y, q4.z, q4.w};
        float kv[4] = {k4.x, k4.y, k4.z, k4.w};
        #pragma unroll
        for (int a = 0; a < 4; ++a)
            #pragma unroll
            for (int b = 0; b < 4; ++b) acc[a][b] += qv[a] * kv[b];
    }
    #pragma unroll
    for (int a = 0; a < 4; ++a) {
        float4 o;
        o.x = acc[a][0] * 0.125f; o.y = acc[a][1] * 0.125f;
        o.z = acc[a][2] * 0.125f; o.w = acc[a][3] * 0.125f;
        *(float4*)&aff[(((size_t)(c * GG + g)) * NT + i0 + ty * 4 + a) * NT + j0 + tx * 4] = o;
    }
}

// ---------------------------------------------------------------------------
// K2b1: producer-consumer ping-pong scan.
//   Block = (j-chunk of 256, 8-row i-tile, c); 8 tiles of 32 j.
//   Waves 0-1 (t<128): w_g GEMM for tile s  -> wgl[s&1]   (2 rows x 16 g /thr)
//   Waves 2-3        : top-10 scan of tile s-1 from wgl[(s-1)&1]
//   One __syncthreads per step; phases fully overlap.
// ---------------------------------------------------------------------------
__global__ __launch_bounds__(256) void k2b1_scan(
    const float* __restrict__ pe, const float* __restrict__ iou,
    const float* __restrict__ WGw, const float* __restrict__ WGb,
    const float* __restrict__ aff,
    float* __restrict__ cv, int* __restrict__ ci)
{
    const int ch = blockIdx.x;   // 0..3
    const int it = blockIdx.y;   // 0..127
    const int c  = blockIdx.z;
    const int i0 = it * 8;

    __shared__ float wgw[16][64];
    __shared__ float wgb_s[16];
    __shared__ float wgl[2][8][16][33];   // ping-pong [i][g][j(32)+pad]

    const int t = threadIdx.x;
    ((float4*)&wgw[0][0])[t] = ((const float4*)WGw)[t];   // 1024 floats
    if (t < 16) wgb_s[t] = WGb[t];

    float tv[10]; int tidx[10];
    #pragma unroll
    for (int q = 0; q < 10; ++q) { tv[q] = NEG_BIG; tidx[q] = 0; }

    const bool prod = (t < 128);
    const int p_i = t >> 4, jq = t & 15;              // producer map
    const int u = t - 128;
    const int s_i = (u >> 4) & 7, s_g = u & 15;       // consumer map

    __syncthreads();

    for (int s = 0; s < 9; ++s) {
        if (prod) {
            if (s < 8) {
                const int j0 = ch * 256 + s * 32;
                float acc0[16], acc1[16];
                #pragma unroll
                for (int g = 0; g < 16; ++g) { acc0[g] = wgb_s[g]; acc1[g] = wgb_s[g]; }
                const float* r0 = &pe[(((size_t)c * NT + (i0 + p_i)) * NT + (j0 + jq)) * 64];
                const float* r1 = r0 + 16 * 64;
                #pragma unroll
                for (int db = 0; db < 64; db += 16) {
                    float4 b0[4], b1[4];
                    #pragma unroll
                    for (int k = 0; k < 4; ++k) b0[k] = *(const float4*)&r0[db + k * 4];
                    #pragma unroll
                    for (int k = 0; k < 4; ++k) b1[k] = *(const float4*)&r1[db + k * 4];
                    #pragma unroll
                    for (int k = 0; k < 4; ++k) {
                        #pragma unroll
                        for (int g = 0; g < 16; ++g) {
                            float4 w4 = *(const float4*)&wgw[g][db + k * 4];
                            acc0[g] += b0[k].x * w4.x + b0[k].y * w4.y
                                     + b0[k].z * w4.z + b0[k].w * w4.w;
                            acc1[g] += b1[k].x * w4.x + b1[k].y * w4.y
                                     + b1[k].z * w4.z + b1[k].w * w4.w;
                        }
                    }
                }
                float* wb = &wgl[s & 1][p_i][0][0];
                #pragma unroll
                for (int g = 0; g < 16; ++g) {
                    wb[g * 33 + jq]      = (acc0[g] > 1e-6f) ? __logf(acc0[g]) : LOG1E6;
                    wb[g * 33 + jq + 16] = (acc1[g] > 1e-6f) ? __logf(acc1[g]) : LOG1E6;
                }
            }
        } else {
            if (s >= 1) {
                const int ts = s - 1;
                const int j0 = ch * 256 + ts * 32;
                const float* ar   = &aff[(((size_t)(c * GG + s_g)) * NT + (i0 + s_i)) * NT + j0];
                const float* orow = &iou[((size_t)c * NT + (i0 + s_i)) * NT + j0];
                const float* wl   = &wgl[ts & 1][s_i][s_g][0];
                #pragma unroll
                for (int j4 = 0; j4 < 32; j4 += 4) {
                    float4 a4 = *(const float4*)&ar[j4];
                    float4 o4 = *(const float4*)&orow[j4];
                    float av[4] = {a4.x, a4.y, a4.z, a4.w};
                    float ov[4] = {o4.x, o4.y, o4.z, o4.w};
                    #pragma unroll
                    for (int q = 0; q < 4; ++q) {
                        const int j = j4 + q;
                        const float val = wl[j] + av[q] + ((ov[q] >= 1e-6f) ? 0.f : LOG1E6);
                        if (val > tv[0]) {
                            const int ix = j0 + j;
                            #pragma unroll
                            for (int sl = 0; sl < 10; ++sl) {
                                const bool up   = (sl < 9) ? (val > tv[sl + 1]) : false;
                                const bool here = (val > tv[sl]);
                                const float ntv = up ? tv[sl + 1] : (here ? val : tv[sl]);
                                const int   nti = up ? tidx[sl + 1] : (here ? ix : tidx[sl]);
                                tv[sl] = ntv; tidx[sl] = nti;
                            }
                        }
                    }
                }
            }
        }
        __syncthreads();
    }

    if (!prod) {
        const size_t base = ((((size_t)c * NT + (i0 + s_i)) * GG + s_g) * 4 + ch) * 10;
        #pragma unroll
        for (int q = 0; q < 10; ++q) { cv[base + q] = tv[q]; ci[base + q] = tidx[q]; }
    }
}

// ---------------------------------------------------------------------------
// K2b2: one 64-lane wave per (c,i,g) row; redundant merge of 4x10 sorted
//       (ascending) chunk lists scanned DESCENDING; softmax; coalesced
//       V-gather (lane = output dim in the 64-wide g-slice).
// ---------------------------------------------------------------------------
__global__ __launch_bounds__(256) void k2b2_fin(
    const float* __restrict__ cv, const int* __restrict__ ci,
    const float* __restrict__ V, float* __restrict__ y)
{
    const int w    = (blockIdx.x << 2) + (threadIdx.x >> 6);
    const int lane = threadIdx.x & 63;
    const int c = w >> 14;
    const int i = (w >> 4) & (NT - 1);
    const int g = w & 15;

    float tv[10]; int tidx[10];
    #pragma unroll
    for (int q = 0; q < 10; ++q) { tv[q] = NEG_BIG; tidx[q] = 0; }

    const size_t base = (size_t)w * 40;
    for (int chn = 0; chn < 4; ++chn) {
        const float* cvp = &cv[base + chn * 10];
        const int*   cip = &ci[base + chn * 10];
        for (int q = 9; q >= 0; --q) {      // descending: early-fail after warmup
            const float val = cvp[q];
            const int   ix  = cip[q];
            if (val > tv[0]) {              // wave-uniform branch
                #pragma unroll
                for (int sl = 0; sl < 10; ++sl) {
                    const bool up   = (sl < 9) ? (val > tv[sl + 1]) : false;
                    const bool here = (val > tv[sl]);
                    const float ntv = up ? tv[sl + 1] : (here ? val : tv[sl]);
                    const int   nti = up ? tidx[sl + 1] : (here ? ix : tidx[sl]);
                    tv[sl] = ntv; tidx[sl] = nti;
                }
            }
        }
    }
    const float m = tv[9];
    float wgt[10]; float sm = 0.f;
    #pragma unroll
    for (int q = 0; q < 10; ++q) { wgt[q] = __expf(tv[q] - m); sm += wgt[q]; }
    const float inv = 1.f / sm;
    float o = 0.f;
    #pragma unroll
    for (int q = 0; q < 10; ++q)
        o += (wgt[q] * inv) * V[((size_t)(c * NT + tidx[q])) * DD + g * 64 + lane];
    y[((size_t)i * CD + c) * DD + g * 64 + lane] = o;
}

extern "C" void kernel_launch(void* const* d_in, const int* in_sizes, int n_in,
                              void* d_out, int out_size, void* d_ws, size_t ws_size,
                              hipStream_t stream) {
    (void)in_sizes; (void)n_in; (void)out_size; (void)ws_size;
    const float* f_a = (const float*)d_in[0];
    const float* pe  = (const float*)d_in[1];
    const float* iou = (const float*)d_in[2];
    const float* WGw = (const float*)d_in[3];
    const float* WGb = (const float*)d_in[4];
    const float* WKw = (const float*)d_in[5];
    const float* WKb = (const float*)d_in[6];
    const float* WQw = (const float*)d_in[7];
    const float* WQb = (const float*)d_in[8];
    const float* Cw  = (const float*)d_in[9];
    const float* Cb  = (const float*)d_in[10];
    float* yout = (float*)d_out;

    // ws floats: Q [2^21] | K [2^21] | V [2^21] | aff [2^25]  (~159.4 MB)
    // cv overlays Q, ci overlays K after k2a (Q/K dead by then).
    float* ws  = (float*)d_ws;
    float* Q   = ws;
    float* Kp  = ws + (1u << 21);
    float* V   = ws + (2u << 21);
    float* aff = ws + (3u << 21);
    float* cv  = ws;
    int*   ci  = (int*)(ws + (1u << 21));

    k1_proj<<<dim3(16, 16, 3), 256, 0, stream>>>(f_a, WQw, WQb, WKw, WKb, Cw, Cb, Q, Kp, V);
    k2a_aff<<<dim3(16, 16, 32), 256, 0, stream>>>(Q, Kp, aff);
    k2b1_scan<<<dim3(4, 128, 2), 256, 0, stream>>>(pe, iou, WGw, WGb, aff, cv, ci);
    k2b2_fin<<<8192, 256, 0, stream>>>(cv, ci, V, yout);
}

// Round 4
// 649.320 us; speedup vs baseline: 1.2866x; 1.2866x over previous
//
#include <hip/hip_runtime.h>
#include <math.h>

#define NT 1024
#define CD 2
#define DD 1024
#define GG 16
#define LOG1E6 -13.8155105579642740f
#define NEG_BIG -1e30f

// ---------------------------------------------------------------------------
// K1: fp32 GEMM  P_z[r][e] = sum_d A[r][d] * W_z[e][d] + b_z[e]
//     tile 128 rows x 64 cols, BK=32, 256 threads, 8x4 micro-tile
// ---------------------------------------------------------------------------
__global__ __launch_bounds__(256) void k1_proj(
    const float* __restrict__ fa,
    const float* __restrict__ Wq, const float* __restrict__ bq,
    const float* __restrict__ Wk, const float* __restrict__ bk,
    const float* __restrict__ Wc, const float* __restrict__ bc,
    float* __restrict__ Qo, float* __restrict__ Ko, float* __restrict__ Vo)
{
    const int et = blockIdx.x, rt = blockIdx.y, z = blockIdx.z;
    const float* W  = (z == 0) ? Wq : (z == 1) ? Wk : Wc;
    const float* bb = (z == 0) ? bq : (z == 1) ? bk : bc;
    float* Out      = (z == 0) ? Qo : (z == 1) ? Ko : Vo;

    __shared__ float Al[32][132];
    __shared__ float Wl[32][68];

    const int t  = threadIdx.x;
    const int tx = t & 15, ty = t >> 4;
    const int dd = t & 7,  rr = t >> 3;
    const int r0 = rt * 128, e0 = et * 64;

    float acc[8][4];
    #pragma unroll
    for (int a = 0; a < 8; ++a)
        #pragma unroll
        for (int b = 0; b < 4; ++b) acc[a][b] = 0.f;

    for (int kt = 0; kt < 32; ++kt) {
        const int db = kt * 32 + dd * 4;
        #pragma unroll
        for (int p = 0; p < 4; ++p) {
            const int row = rr + p * 32;
            const int r = r0 + row;
            const int n = r & (NT - 1), c = r >> 10;
            float4 a4 = *(const float4*)&fa[((size_t)(n * CD + c)) * DD + db];
            Al[dd*4+0][row] = a4.x; Al[dd*4+1][row] = a4.y;
            Al[dd*4+2][row] = a4.z; Al[dd*4+3][row] = a4.w;
        }
        #pragma unroll
        for (int p = 0; p < 2; ++p) {
            const int erow = rr + p * 32;
            float4 w4 = *(const float4*)&W[((size_t)(e0 + erow)) * DD + db];
            Wl[dd*4+0][erow] = w4.x; Wl[dd*4+1][erow] = w4.y;
            Wl[dd*4+2][erow] = w4.z; Wl[dd*4+3][erow] = w4.w;
        }
        __syncthreads();
        #pragma unroll 4
        for (int d = 0; d < 32; ++d) {
            float4 a0 = *(const float4*)&Al[d][ty * 8];
            float4 a1 = *(const float4*)&Al[d][ty * 8 + 4];
            float4 w4 = *(const float4*)&Wl[d][tx * 4];
            float av[8] = {a0.x, a0.y, a0.z, a0.w, a1.x, a1.y, a1.z, a1.w};
            float wv[4] = {w4.x, w4.y, w4.z, w4.w};
            #pragma unroll
            for (int a = 0; a < 8; ++a)
                #pragma unroll
                for (int b = 0; b < 4; ++b) acc[a][b] += av[a] * wv[b];
        }
        __syncthreads();
    }
    float4 b4 = *(const float4*)&bb[e0 + tx * 4];
    #pragma unroll
    for (int a = 0; a < 8; ++a) {
        float4 o;
        o.x = acc[a][0] + b4.x; o.y = acc[a][1] + b4.y;
        o.z = acc[a][2] + b4.z; o.w = acc[a][3] + b4.w;
        *(float4*)&Out[((size_t)(r0 + ty * 8 + a)) * DD + e0 + tx * 4] = o;
    }
}

// ---------------------------------------------------------------------------
// K2a: aff[c][g][i][j] = (sum_d Q[c,i,g*64+d] * K[c,j,g*64+d]) / 8
// ---------------------------------------------------------------------------
__global__ __launch_bounds__(256) void k2a_aff(
    const float* __restrict__ Q, const float* __restrict__ Km,
    float* __restrict__ aff)
{
    const int jt = blockIdx.x, it = blockIdx.y, cg = blockIdx.z;
    const int c = cg >> 4, g = cg & 15;
    __shared__ float Ql[64][68];
    __shared__ float Kl[64][68];
    const int t = threadIdx.x;
    const int dd = t & 15, rr = t >> 4;
    const int i0 = it * 64, j0 = jt * 64;
    #pragma unroll
    for (int p = 0; p < 4; ++p) {
        const int row = rr + p * 16;
        float4 q4 = *(const float4*)&Q[((size_t)(c * NT + i0 + row)) * DD + g * 64 + dd * 4];
        Ql[dd*4+0][row] = q4.x; Ql[dd*4+1][row] = q4.y;
        Ql[dd*4+2][row] = q4.z; Ql[dd*4+3][row] = q4.w;
        float4 k4 = *(const float4*)&Km[((size_t)(c * NT + j0 + row)) * DD + g * 64 + dd * 4];
        Kl[dd*4+0][row] = k4.x; Kl[dd*4+1][row] = k4.y;
        Kl[dd*4+2][row] = k4.z; Kl[dd*4+3][row] = k4.w;
    }
    __syncthreads();
    const int tx = t & 15, ty = t >> 4;
    float acc[4][4];
    #pragma unroll
    for (int a = 0; a < 4; ++a)
        #pragma unroll
        for (int b = 0; b < 4; ++b) acc[a][b] = 0.f;
    #pragma unroll 8
    for (int d = 0; d < 64; ++d) {
        float4 q4 = *(const float4*)&Ql[d][ty * 4];
        float4 k4 = *(const float4*)&Kl[d][tx * 4];
        float qv[4] = {q4.x, q4.y, q4.z, q4.w};
        float kv[4] = {k4.x, k4.y, k4.z, k4.w};
        #pragma unroll
        for (int a = 0; a < 4; ++a)
            #pragma unroll
            for (int b = 0; b < 4; ++b) acc[a][b] += qv[a] * kv[b];
    }
    #pragma unroll
    for (int a = 0; a < 4; ++a) {
        float4 o;
        o.x = acc[a][0] * 0.125f; o.y = acc[a][1] * 0.125f;
        o.z = acc[a][2] * 0.125f; o.w = acc[a][3] * 0.125f;
        *(float4*)&aff[(((size_t)(c * GG + g)) * NT + i0 + ty * 4 + a) * NT + j0 + tx * 4] = o;
    }
}

// ---------------------------------------------------------------------------
// K2bA: dense w_mn, IN-PLACE over aff (layout [c][g][i][j]).
//   Block = (64-j tile, 8-i tile, c); thread = (i, jq) handles 2 j x 16 g.
//   wmn[c,g,i,j] = aff[c,g,i,j] + log(clip(relu(pe.WG+b))) + log_iou.
//   Each element read+written by exactly one thread -> no race.
//   No barriers after the 4KB wgw staging; pure streaming.
// ---------------------------------------------------------------------------
__global__ __launch_bounds__(256) void k2bA_dense(
    const float* __restrict__ pe, const float* __restrict__ iou,
    const float* __restrict__ WGw, const float* __restrict__ WGb,
    float* __restrict__ wmn)
{
    const int jt = blockIdx.x;   // 0..15
    const int it = blockIdx.y;   // 0..127
    const int c  = blockIdx.z;

    __shared__ float wgw[16][64];
    __shared__ float wgb_s[16];
    const int t = threadIdx.x;
    ((float4*)&wgw[0][0])[t] = ((const float4*)WGw)[t];   // 1024 floats
    if (t < 16) wgb_s[t] = WGb[t];
    __syncthreads();

    const int p_i = t >> 5;        // 0..7
    const int jq  = t & 31;        // 0..31
    const int i   = it * 8 + p_i;
    const int ja  = jt * 64 + jq;
    const int jb  = ja + 32;

    float acc0[16], acc1[16];
    #pragma unroll
    for (int g = 0; g < 16; ++g) { acc0[g] = wgb_s[g]; acc1[g] = wgb_s[g]; }

    const float* r0 = &pe[(((size_t)c * NT + i) * NT + ja) * 64];
    const float* r1 = r0 + 32 * 64;

    #pragma unroll 1
    for (int db = 0; db < 64; db += 16) {
        float4 pa[4], pb[4];
        #pragma unroll
        for (int k = 0; k < 4; ++k) pa[k] = *(const float4*)&r0[db + 4 * k];
        #pragma unroll
        for (int k = 0; k < 4; ++k) pb[k] = *(const float4*)&r1[db + 4 * k];
        #pragma unroll
        for (int g = 0; g < 16; ++g) {
            #pragma unroll
            for (int k = 0; k < 4; ++k) {
                float4 w = *(const float4*)&wgw[g][db + 4 * k];
                acc0[g] += pa[k].x * w.x + pa[k].y * w.y + pa[k].z * w.z + pa[k].w * w.w;
                acc1[g] += pb[k].x * w.x + pb[k].y * w.y + pb[k].z * w.z + pb[k].w * w.w;
            }
        }
    }

    const float lio_a = (iou[((size_t)c * NT + i) * NT + ja] >= 1e-6f) ? 0.f : LOG1E6;
    const float lio_b = (iou[((size_t)c * NT + i) * NT + jb] >= 1e-6f) ? 0.f : LOG1E6;

    #pragma unroll
    for (int g = 0; g < 16; ++g) {
        float* ap = &wmn[(((size_t)c * GG + g) * NT + i) * NT];
        const float wa = acc0[g], wb = acc1[g];
        const float la = (wa > 1e-6f) ? __logf(wa) : LOG1E6;
        const float lb = (wb > 1e-6f) ? __logf(wb) : LOG1E6;
        ap[ja] += la + lio_a;
        ap[jb] += lb + lio_b;
    }
}

// ---------------------------------------------------------------------------
// K2bB: chunk top-10 scan of dense wmn. Thread = (c,g,i,chunk of 256 j),
//   reads its chunk contiguously (float4), writes 10 candidates.
// ---------------------------------------------------------------------------
__global__ __launch_bounds__(256) void k2bB_scan(
    const float* __restrict__ wmn,
    float* __restrict__ cv, int* __restrict__ ci)
{
    const int tid = blockIdx.x * 256 + threadIdx.x;   // 131072
    const int ch = tid & 3;
    const int g  = (tid >> 2) & 15;
    const int i  = (tid >> 6) & (NT - 1);
    const int c  = tid >> 16;

    const float* row = &wmn[(((size_t)c * GG + g) * NT + i) * NT + ch * 256];

    float tv[10]; int tidx[10];
    #pragma unroll
    for (int q = 0; q < 10; ++q) { tv[q] = NEG_BIG; tidx[q] = 0; }

    #pragma unroll 4
    for (int j4 = 0; j4 < 256; j4 += 4) {
        float4 v4 = *(const float4*)&row[j4];
        float vv[4] = {v4.x, v4.y, v4.z, v4.w};
        #pragma unroll
        for (int q = 0; q < 4; ++q) {
            const float val = vv[q];
            if (val > tv[0]) {
                const int ix = ch * 256 + j4 + q;
                #pragma unroll
                for (int sl = 0; sl < 10; ++sl) {
                    const bool up   = (sl < 9) ? (val > tv[sl + 1]) : false;
                    const bool here = (val > tv[sl]);
                    const float ntv = up ? tv[sl + 1] : (here ? val : tv[sl]);
                    const int   nti = up ? tidx[sl + 1] : (here ? ix : tidx[sl]);
                    tv[sl] = ntv; tidx[sl] = nti;
                }
            }
        }
    }
    const size_t base = ((((size_t)c * NT + i) * GG + g) * 4 + ch) * 10;
    #pragma unroll
    for (int q = 0; q < 10; ++q) { cv[base + q] = tv[q]; ci[base + q] = tidx[q]; }
}

// ---------------------------------------------------------------------------
// K2b2: one 64-lane wave per (c,i,g) row; redundant merge of 4x10 sorted
//       (ascending) chunk lists scanned DESCENDING; softmax; coalesced
//       V-gather (lane = output dim in the 64-wide g-slice).
// ---------------------------------------------------------------------------
__global__ __launch_bounds__(256) void k2b2_fin(
    const float* __restrict__ cv, const int* __restrict__ ci,
    const float* __restrict__ V, float* __restrict__ y)
{
    const int w    = (blockIdx.x << 2) + (threadIdx.x >> 6);
    const int lane = threadIdx.x & 63;
    const int c = w >> 14;
    const int i = (w >> 4) & (NT - 1);
    const int g = w & 15;

    float tv[10]; int tidx[10];
    #pragma unroll
    for (int q = 0; q < 10; ++q) { tv[q] = NEG_BIG; tidx[q] = 0; }

    const size_t base = (size_t)w * 40;
    for (int chn = 0; chn < 4; ++chn) {
        const float* cvp = &cv[base + chn * 10];
        const int*   cip = &ci[base + chn * 10];
        for (int q = 9; q >= 0; --q) {
            const float val = cvp[q];
            const int   ix  = cip[q];
            if (val > tv[0]) {
                #pragma unroll
                for (int sl = 0; sl < 10; ++sl) {
                    const bool up   = (sl < 9) ? (val > tv[sl + 1]) : false;
                    const bool here = (val > tv[sl]);
                    const float ntv = up ? tv[sl + 1] : (here ? val : tv[sl]);
                    const int   nti = up ? tidx[sl + 1] : (here ? ix : tidx[sl]);
                    tv[sl] = ntv; tidx[sl] = nti;
                }
            }
        }
    }
    const float m = tv[9];
    float wgt[10]; float sm = 0.f;
    #pragma unroll
    for (int q = 0; q < 10; ++q) { wgt[q] = __expf(tv[q] - m); sm += wgt[q]; }
    const float inv = 1.f / sm;
    float o = 0.f;
    #pragma unroll
    for (int q = 0; q < 10; ++q)
        o += (wgt[q] * inv) * V[((size_t)(c * NT + tidx[q])) * DD + g * 64 + lane];
    y[((size_t)i * CD + c) * DD + g * 64 + lane] = o;
}

extern "C" void kernel_launch(void* const* d_in, const int* in_sizes, int n_in,
                              void* d_out, int out_size, void* d_ws, size_t ws_size,
                              hipStream_t stream) {
    (void)in_sizes; (void)n_in; (void)out_size; (void)ws_size;
    const float* f_a = (const float*)d_in[0];
    const float* pe  = (const float*)d_in[1];
    const float* iou = (const float*)d_in[2];
    const float* WGw = (const float*)d_in[3];
    const float* WGb = (const float*)d_in[4];
    const float* WKw = (const float*)d_in[5];
    const float* WKb = (const float*)d_in[6];
    const float* WQw = (const float*)d_in[7];
    const float* WQb = (const float*)d_in[8];
    const float* Cw  = (const float*)d_in[9];
    const float* Cb  = (const float*)d_in[10];
    float* yout = (float*)d_out;

    // ws floats: Q [2^21] | K [2^21] | V [2^21] | aff/wmn [2^25]  (~159.4 MB)
    // aff is transformed IN-PLACE into wmn by k2bA. cv overlays Q, ci overlays
    // K after k2a (both dead by then).
    float* ws  = (float*)d_ws;
    float* Q   = ws;
    float* Kp  = ws + (1u << 21);
    float* V   = ws + (2u << 21);
    float* aff = ws + (3u << 21);
    float* cv  = ws;
    int*   ci  = (int*)(ws + (1u << 21));

    k1_proj<<<dim3(16, 16, 3), 256, 0, stream>>>(f_a, WQw, WQb, WKw, WKb, Cw, Cb, Q, Kp, V);
    k2a_aff<<<dim3(16, 16, 32), 256, 0, stream>>>(Q, Kp, aff);
    k2bA_dense<<<dim3(16, 128, 2), 256, 0, stream>>>(pe, iou, WGw, WGb, aff);
    k2bB_scan<<<512, 256, 0, stream>>>(aff, cv, ci);
    k2b2_fin<<<8192, 256, 0, stream>>>(cv, ci, V, yout);
}

// Round 6
// 614.355 us; speedup vs baseline: 1.3598x; 1.0569x over previous
//
#include <hip/hip_runtime.h>
#include <math.h>

#define NT 1024
#define CD 2
#define DD 1024
#define GG 16
#define LOG1E6 -13.8155105579642740f
#define NEG_BIG -1e30f

// ---------------------------------------------------------------------------
// K1: fp32 GEMM  P_z[r][e] = sum_d A[r][d] * W_z[e][d] + b_z[e]
//     tile 128 rows x 64 cols, BK=32, 256 threads, 8x4 micro-tile
//     (fp32 VALU on purpose: split-bf16 MFMA's ~1e-5 aff error widens the
//      top-k tie window 10x and flips ranks -> 0.145 absmax in R5.)
// ---------------------------------------------------------------------------
__global__ __launch_bounds__(256) void k1_proj(
    const float* __restrict__ fa,
    const float* __restrict__ Wq, const float* __restrict__ bq,
    const float* __restrict__ Wk, const float* __restrict__ bk,
    const float* __restrict__ Wc, const float* __restrict__ bc,
    float* __restrict__ Qo, float* __restrict__ Ko, float* __restrict__ Vo)
{
    const int et = blockIdx.x, rt = blockIdx.y, z = blockIdx.z;
    const float* W  = (z == 0) ? Wq : (z == 1) ? Wk : Wc;
    const float* bb = (z == 0) ? bq : (z == 1) ? bk : bc;
    float* Out      = (z == 0) ? Qo : (z == 1) ? Ko : Vo;

    __shared__ float Al[32][132];
    __shared__ float Wl[32][68];

    const int t  = threadIdx.x;
    const int tx = t & 15, ty = t >> 4;
    const int dd = t & 7,  rr = t >> 3;
    const int r0 = rt * 128, e0 = et * 64;

    float acc[8][4];
    #pragma unroll
    for (int a = 0; a < 8; ++a)
        #pragma unroll
        for (int b = 0; b < 4; ++b) acc[a][b] = 0.f;

    for (int kt = 0; kt < 32; ++kt) {
        const int db = kt * 32 + dd * 4;
        #pragma unroll
        for (int p = 0; p < 4; ++p) {
            const int row = rr + p * 32;
            const int r = r0 + row;
            const int n = r & (NT - 1), c = r >> 10;
            float4 a4 = *(const float4*)&fa[((size_t)(n * CD + c)) * DD + db];
            Al[dd*4+0][row] = a4.x; Al[dd*4+1][row] = a4.y;
            Al[dd*4+2][row] = a4.z; Al[dd*4+3][row] = a4.w;
        }
        #pragma unroll
        for (int p = 0; p < 2; ++p) {
            const int erow = rr + p * 32;
            float4 w4 = *(const float4*)&W[((size_t)(e0 + erow)) * DD + db];
            Wl[dd*4+0][erow] = w4.x; Wl[dd*4+1][erow] = w4.y;
            Wl[dd*4+2][erow] = w4.z; Wl[dd*4+3][erow] = w4.w;
        }
        __syncthreads();
        #pragma unroll 4
        for (int d = 0; d < 32; ++d) {
            float4 a0 = *(const float4*)&Al[d][ty * 8];
            float4 a1 = *(const float4*)&Al[d][ty * 8 + 4];
            float4 w4 = *(const float4*)&Wl[d][tx * 4];
            float av[8] = {a0.x, a0.y, a0.z, a0.w, a1.x, a1.y, a1.z, a1.w};
            float wv[4] = {w4.x, w4.y, w4.z, w4.w};
            #pragma unroll
            for (int a = 0; a < 8; ++a)
                #pragma unroll
                for (int b = 0; b < 4; ++b) acc[a][b] += av[a] * wv[b];
        }
        __syncthreads();
    }
    float4 b4 = *(const float4*)&bb[e0 + tx * 4];
    #pragma unroll
    for (int a = 0; a < 8; ++a) {
        float4 o;
        o.x = acc[a][0] + b4.x; o.y = acc[a][1] + b4.y;
        o.z = acc[a][2] + b4.z; o.w = acc[a][3] + b4.w;
        *(float4*)&Out[((size_t)(r0 + ty * 8 + a)) * DD + e0 + tx * 4] = o;
    }
}

// ---------------------------------------------------------------------------
// K2a: aff[c][g][i][j] = (sum_d Q[c,i,g*64+d] * K[c,j,g*64+d]) / 8   (fp32)
// ---------------------------------------------------------------------------
__global__ __launch_bounds__(256) void k2a_aff(
    const float* __restrict__ Q, const float* __restrict__ Km,
    float* __restrict__ aff)
{
    const int jt = blockIdx.x, it = blockIdx.y, cg = blockIdx.z;
    const int c = cg >> 4, g = cg & 15;
    __shared__ float Ql[64][68];
    __shared__ float Kl[64][68];
    const int t = threadIdx.x;
    const int dd = t & 15, rr = t >> 4;
    const int i0 = it * 64, j0 = jt * 64;
    #pragma unroll
    for (int p = 0; p < 4; ++p) {
        const int row = rr + p * 16;
        float4 q4 = *(const float4*)&Q[((size_t)(c * NT + i0 + row)) * DD + g * 64 + dd * 4];
        Ql[dd*4+0][row] = q4.x; Ql[dd*4+1][row] = q4.y;
        Ql[dd*4+2][row] = q4.z; Ql[dd*4+3][row] = q4.w;
        float4 k4 = *(const float4*)&Km[((size_t)(c * NT + j0 + row)) * DD + g * 64 + dd * 4];
        Kl[dd*4+0][row] = k4.x; Kl[dd*4+1][row] = k4.y;
        Kl[dd*4+2][row] = k4.z; Kl[dd*4+3][row] = k4.w;
    }
    __syncthreads();
    const int tx = t & 15, ty = t >> 4;
    float acc[4][4];
    #pragma unroll
    for (int a = 0; a < 4; ++a)
        #pragma unroll
        for (int b = 0; b < 4; ++b) acc[a][b] = 0.f;
    #pragma unroll 8
    for (int d = 0; d < 64; ++d) {
        float4 q4 = *(const float4*)&Ql[d][ty * 4];
        float4 k4 = *(const float4*)&Kl[d][tx * 4];
        float qv[4] = {q4.x, q4.y, q4.z, q4.w};
        float kv[4] = {k4.x, k4.y, k4.z, k4.w};
        #pragma unroll
        for (int a = 0; a < 4; ++a)
            #pragma unroll
            for (int b = 0; b < 4; ++b) acc[a][b] += qv[a] * kv[b];
    }
    #pragma unroll
    for (int a = 0; a < 4; ++a) {
        float4 o;
        o.x = acc[a][0] * 0.125f; o.y = acc[a][1] * 0.125f;
        o.z = acc[a][2] * 0.125f; o.w = acc[a][3] * 0.125f;
        *(float4*)&aff[(((size_t)(c * GG + g)) * NT + i0 + ty * 4 + a) * NT + j0 + tx * 4] = o;
    }
}

// ---------------------------------------------------------------------------
// K3: fused dense + top-10 scan. Block = (256-j chunk, 8-i tile, c).
//   4 subtiles of 64 j:
//     Phase G (all 256 thr): wg GEMM (2j x 16g each) -> log -> LDS; iou -> LDS.
//     Phase S (all 256 thr): thread=(i,g,half32) scans 32 j, top-10 in regs.
//   End: merge h0/h1 lists via LDS, write 10 candidates per (c,i,g,chunk).
// ---------------------------------------------------------------------------
__global__ __launch_bounds__(256) void k3_scan(
    const float* __restrict__ pe, const float* __restrict__ iou,
    const float* __restrict__ WGw, const float* __restrict__ WGb,
    const float* __restrict__ aff,
    float* __restrict__ cv, int* __restrict__ ci)
{
    const int ch = blockIdx.x;   // 0..3
    const int it = blockIdx.y;   // 0..127
    const int c  = blockIdx.z;
    const int i0 = it * 8;

    __shared__ float wgw[16][64];
    __shared__ float wgb_s[16];
    __shared__ float wgl[8][16][65];   // [i][g][j], <=2-way banks on writes
    __shared__ float ios[8][65];       // log_iou staging [i][j]

    const int t = threadIdx.x;
    ((float4*)&wgw[0][0])[t] = ((const float4*)WGw)[t];   // 1024 floats
    if (t < 16) wgb_s[t] = WGb[t];
    __syncthreads();

    const int p_i = t >> 5, jq = t & 31;            // phase-G map
    const int s_i = t >> 5, s_g = (t >> 1) & 15, s_h = t & 1;  // phase-S map

    float tv[10]; int tidx[10];
    #pragma unroll
    for (int q = 0; q < 10; ++q) { tv[q] = NEG_BIG; tidx[q] = 0; }

    for (int s = 0; s < 4; ++s) {
        const int j0 = ch * 256 + s * 64;
        // ---- phase G ----
        float acc0[16], acc1[16];
        #pragma unroll
        for (int g = 0; g < 16; ++g) { acc0[g] = wgb_s[g]; acc1[g] = wgb_s[g]; }
        const float* r0 = &pe[(((size_t)c * NT + (i0 + p_i)) * NT + (j0 + jq)) * 64];
        const float* r1 = r0 + 32 * 64;
        #pragma unroll 1
        for (int db = 0; db < 64; db += 16) {
            float4 pa[4], pb[4];
            #pragma unroll
            for (int k = 0; k < 4; ++k) pa[k] = *(const float4*)&r0[db + 4 * k];
            #pragma unroll
            for (int k = 0; k < 4; ++k) pb[k] = *(const float4*)&r1[db + 4 * k];
            #pragma unroll
            for (int g = 0; g < 16; ++g) {
                #pragma unroll
                for (int k = 0; k < 4; ++k) {
                    float4 w = *(const float4*)&wgw[g][db + 4 * k];
                    acc0[g] += pa[k].x * w.x + pa[k].y * w.y + pa[k].z * w.z + pa[k].w * w.w;
                    acc1[g] += pb[k].x * w.x + pb[k].y * w.y + pb[k].z * w.z + pb[k].w * w.w;
                }
            }
        }
        {
            const float ia = iou[((size_t)c * NT + (i0 + p_i)) * NT + j0 + jq];
            const float ib = iou[((size_t)c * NT + (i0 + p_i)) * NT + j0 + jq + 32];
            ios[p_i][jq]      = (ia >= 1e-6f) ? 0.f : LOG1E6;
            ios[p_i][jq + 32] = (ib >= 1e-6f) ? 0.f : LOG1E6;
        }
        float* wb = &wgl[p_i][0][0];
        #pragma unroll
        for (int g = 0; g < 16; ++g) {
            wb[g * 65 + jq]      = (acc0[g] > 1e-6f) ? __logf(acc0[g]) : LOG1E6;
            wb[g * 65 + jq + 32] = (acc1[g] > 1e-6f) ? __logf(acc1[g]) : LOG1E6;
        }
        __syncthreads();
        // ---- phase S ----
        {
            const float* ar = &aff[(((size_t)(c * GG + s_g)) * NT + (i0 + s_i)) * NT + j0 + s_h * 32];
            const float* wl = &wgl[s_i][s_g][s_h * 32];
            const float* il = &ios[s_i][s_h * 32];
            #pragma unroll 2
            for (int j4 = 0; j4 < 32; j4 += 4) {
                float4 a4 = *(const float4*)&ar[j4];
                float av[4] = {a4.x, a4.y, a4.z, a4.w};
                #pragma unroll
                for (int q = 0; q < 4; ++q) {
                    const float val = wl[j4 + q] + av[q] + il[j4 + q];
                    if (val > tv[0]) {
                        const int ix = j0 + s_h * 32 + j4 + q;
                        #pragma unroll
                        for (int sl = 0; sl < 10; ++sl) {
                            const bool up   = (sl < 9) ? (val > tv[sl + 1]) : false;
                            const bool here = (val > tv[sl]);
                            const float ntv = up ? tv[sl + 1] : (here ? val : tv[sl]);
                            const int   nti = up ? tidx[sl + 1] : (here ? ix : tidx[sl]);
                            tv[sl] = ntv; tidx[sl] = nti;
                        }
                    }
                }
            }
        }
        __syncthreads();
    }

    // ---- merge h0/h1 via LDS scratch (reuse wgl: 2560 words needed) ----
    float* mv = &wgl[0][0][0];
    int*   mi = (int*)(mv + 1280);
    const int pair = t >> 1;
    if (s_h == 1) {
        #pragma unroll
        for (int q = 0; q < 10; ++q) { mv[pair * 10 + q] = tv[q]; mi[pair * 10 + q] = tidx[q]; }
    }
    __syncthreads();
    if (s_h == 0) {
        for (int q = 9; q >= 0; --q) {
            const float val = mv[pair * 10 + q];
            const int   ix  = mi[pair * 10 + q];
            if (val > tv[0]) {
                #pragma unroll
                for (int sl = 0; sl < 10; ++sl) {
                    const bool up   = (sl < 9) ? (val > tv[sl + 1]) : false;
                    const bool here = (val > tv[sl]);
                    const float ntv = up ? tv[sl + 1] : (here ? val : tv[sl]);
                    const int   nti = up ? tidx[sl + 1] : (here ? ix : tidx[sl]);
                    tv[sl] = ntv; tidx[sl] = nti;
                }
            }
        }
        const size_t base = ((((size_t)c * NT + (i0 + s_i)) * GG + s_g) * 4 + ch) * 10;
        #pragma unroll
        for (int q = 0; q < 10; ++q) { cv[base + q] = tv[q]; ci[base + q] = tidx[q]; }
    }
}

// ---------------------------------------------------------------------------
// K2b2: one 64-lane wave per (c,i,g) row; merge 4x10 ascending chunk lists
//       (scanned descending), softmax, coalesced V-gather.
// ---------------------------------------------------------------------------
__global__ __launch_bounds__(256) void k2b2_fin(
    const float* __restrict__ cv, const int* __restrict__ ci,
    const float* __restrict__ V, float* __restrict__ y)
{
    const int w    = (blockIdx.x << 2) + (threadIdx.x >> 6);
    const int lane = threadIdx.x & 63;
    const int c = w >> 14;
    const int i = (w >> 4) & (NT - 1);
    const int g = w & 15;

    float tv[10]; int tidx[10];
    #pragma unroll
    for (int q = 0; q < 10; ++q) { tv[q] = NEG_BIG; tidx[q] = 0; }

    const size_t base = (size_t)w * 40;
    for (int chn = 0; chn < 4; ++chn) {
        const float* cvp = &cv[base + chn * 10];
        const int*   cip = &ci[base + chn * 10];
        for (int q = 9; q >= 0; --q) {
            const float val = cvp[q];
            const int   ix  = cip[q];
            if (val > tv[0]) {
                #pragma unroll
                for (int sl = 0; sl < 10; ++sl) {
                    const bool up   = (sl < 9) ? (val > tv[sl + 1]) : false;
                    const bool here = (val > tv[sl]);
                    const float ntv = up ? tv[sl + 1] : (here ? val : tv[sl]);
                    const int   nti = up ? tidx[sl + 1] : (here ? ix : tidx[sl]);
                    tv[sl] = ntv; tidx[sl] = nti;
                }
            }
        }
    }
    const float m = tv[9];
    float wgt[10]; float sm = 0.f;
    #pragma unroll
    for (int q = 0; q < 10; ++q) { wgt[q] = __expf(tv[q] - m); sm += wgt[q]; }
    const float inv = 1.f / sm;
    float o = 0.f;
    #pragma unroll
    for (int q = 0; q < 10; ++q)
        o += (wgt[q] * inv) * V[((size_t)(c * NT + tidx[q])) * DD + g * 64 + lane];
    y[((size_t)i * CD + c) * DD + g * 64 + lane] = o;
}

extern "C" void kernel_launch(void* const* d_in, const int* in_sizes, int n_in,
                              void* d_out, int out_size, void* d_ws, size_t ws_size,
                              hipStream_t stream) {
    (void)in_sizes; (void)n_in; (void)out_size; (void)ws_size;
    const float* f_a = (const float*)d_in[0];
    const float* pe  = (const float*)d_in[1];
    const float* iou = (const float*)d_in[2];
    const float* WGw = (const float*)d_in[3];
    const float* WGb = (const float*)d_in[4];
    const float* WKw = (const float*)d_in[5];
    const float* WKb = (const float*)d_in[6];
    const float* WQw = (const float*)d_in[7];
    const float* WQb = (const float*)d_in[8];
    const float* Cw  = (const float*)d_in[9];
    const float* Cb  = (const float*)d_in[10];
    float* yout = (float*)d_out;

    // ws floats: Q [2^21] | K [2^21] | V [2^21] | aff [2^25]  (~159.4 MB)
    // cv overlays Q, ci overlays K (dead after k2a).
    float* ws  = (float*)d_ws;
    float* Q   = ws;
    float* Kp  = ws + (1u << 21);
    float* V   = ws + (2u << 21);
    float* aff = ws + (3u << 21);
    float* cv  = ws;
    int*   ci  = (int*)(ws + (1u << 21));

    k1_proj<<<dim3(16, 16, 3), 256, 0, stream>>>(f_a, WQw, WQb, WKw, WKb, Cw, Cb, Q, Kp, V);
    k2a_aff<<<dim3(16, 16, 32), 256, 0, stream>>>(Q, Kp, aff);
    k3_scan<<<dim3(4, 128, 2), 256, 0, stream>>>(pe, iou, WGw, WGb, aff, cv, ci);
    k2b2_fin<<<8192, 256, 0, stream>>>(cv, ci, V, yout);
}

// Round 7
// 584.131 us; speedup vs baseline: 1.4302x; 1.0517x over previous
//
#include <hip/hip_runtime.h>
#include <math.h>

#define NT 1024
#define CD 2
#define DD 1024
#define GG 16
#define LOG1E6 -13.8155105579642740f
#define NEG_BIG -1e30f

// ---------------------------------------------------------------------------
// K1: fp32 GEMM  P_z[r][e] = sum_d A[r][d] * W_z[e][d] + b_z[e]
//     tile 128 rows x 64 cols, BK=32, 256 threads, 8x4 micro-tile
//     (fp32 VALU on purpose: split-bf16 MFMA's ~1e-5 aff error widens the
//      top-k tie window 10x and flips ranks -> 0.145 absmax in R5.)
// ---------------------------------------------------------------------------
__global__ __launch_bounds__(256) void k1_proj(
    const float* __restrict__ fa,
    const float* __restrict__ Wq, const float* __restrict__ bq,
    const float* __restrict__ Wk, const float* __restrict__ bk,
    const float* __restrict__ Wc, const float* __restrict__ bc,
    float* __restrict__ Qo, float* __restrict__ Ko, float* __restrict__ Vo)
{
    const int et = blockIdx.x, rt = blockIdx.y, z = blockIdx.z;
    const float* W  = (z == 0) ? Wq : (z == 1) ? Wk : Wc;
    const float* bb = (z == 0) ? bq : (z == 1) ? bk : bc;
    float* Out      = (z == 0) ? Qo : (z == 1) ? Ko : Vo;

    __shared__ float Al[32][132];
    __shared__ float Wl[32][68];

    const int t  = threadIdx.x;
    const int tx = t & 15, ty = t >> 4;
    const int dd = t & 7,  rr = t >> 3;
    const int r0 = rt * 128, e0 = et * 64;

    float acc[8][4];
    #pragma unroll
    for (int a = 0; a < 8; ++a)
        #pragma unroll
        for (int b = 0; b < 4; ++b) acc[a][b] = 0.f;

    for (int kt = 0; kt < 32; ++kt) {
        const int db = kt * 32 + dd * 4;
        #pragma unroll
        for (int p = 0; p < 4; ++p) {
            const int row = rr + p * 32;
            const int r = r0 + row;
            const int n = r & (NT - 1), c = r >> 10;
            float4 a4 = *(const float4*)&fa[((size_t)(n * CD + c)) * DD + db];
            Al[dd*4+0][row] = a4.x; Al[dd*4+1][row] = a4.y;
            Al[dd*4+2][row] = a4.z; Al[dd*4+3][row] = a4.w;
        }
        #pragma unroll
        for (int p = 0; p < 2; ++p) {
            const int erow = rr + p * 32;
            float4 w4 = *(const float4*)&W[((size_t)(e0 + erow)) * DD + db];
            Wl[dd*4+0][erow] = w4.x; Wl[dd*4+1][erow] = w4.y;
            Wl[dd*4+2][erow] = w4.z; Wl[dd*4+3][erow] = w4.w;
        }
        __syncthreads();
        #pragma unroll 4
        for (int d = 0; d < 32; ++d) {
            float4 a0 = *(const float4*)&Al[d][ty * 8];
            float4 a1 = *(const float4*)&Al[d][ty * 8 + 4];
            float4 w4 = *(const float4*)&Wl[d][tx * 4];
            float av[8] = {a0.x, a0.y, a0.z, a0.w, a1.x, a1.y, a1.z, a1.w};
            float wv[4] = {w4.x, w4.y, w4.z, w4.w};
            #pragma unroll
            for (int a = 0; a < 8; ++a)
                #pragma unroll
                for (int b = 0; b < 4; ++b) acc[a][b] += av[a] * wv[b];
        }
        __syncthreads();
    }
    float4 b4 = *(const float4*)&bb[e0 + tx * 4];
    #pragma unroll
    for (int a = 0; a < 8; ++a) {
        float4 o;
        o.x = acc[a][0] + b4.x; o.y = acc[a][1] + b4.y;
        o.z = acc[a][2] + b4.z; o.w = acc[a][3] + b4.w;
        *(float4*)&Out[((size_t)(r0 + ty * 8 + a)) * DD + e0 + tx * 4] = o;
    }
}

// ---------------------------------------------------------------------------
// K2a: aff[c][g][i][j] = (sum_d Q[c,i,g*64+d] * K[c,j,g*64+d]) / 8   (fp32)
// ---------------------------------------------------------------------------
__global__ __launch_bounds__(256) void k2a_aff(
    const float* __restrict__ Q, const float* __restrict__ Km,
    float* __restrict__ aff)
{
    const int jt = blockIdx.x, it = blockIdx.y, cg = blockIdx.z;
    const int c = cg >> 4, g = cg & 15;
    __shared__ float Ql[64][68];
    __shared__ float Kl[64][68];
    const int t = threadIdx.x;
    const int dd = t & 15, rr = t >> 4;
    const int i0 = it * 64, j0 = jt * 64;
    #pragma unroll
    for (int p = 0; p < 4; ++p) {
        const int row = rr + p * 16;
        float4 q4 = *(const float4*)&Q[((size_t)(c * NT + i0 + row)) * DD + g * 64 + dd * 4];
        Ql[dd*4+0][row] = q4.x; Ql[dd*4+1][row] = q4.y;
        Ql[dd*4+2][row] = q4.z; Ql[dd*4+3][row] = q4.w;
        float4 k4 = *(const float4*)&Km[((size_t)(c * NT + j0 + row)) * DD + g * 64 + dd * 4];
        Kl[dd*4+0][row] = k4.x; Kl[dd*4+1][row] = k4.y;
        Kl[dd*4+2][row] = k4.z; Kl[dd*4+3][row] = k4.w;
    }
    __syncthreads();
    const int tx = t & 15, ty = t >> 4;
    float acc[4][4];
    #pragma unroll
    for (int a = 0; a < 4; ++a)
        #pragma unroll
        for (int b = 0; b < 4; ++b) acc[a][b] = 0.f;
    #pragma unroll 8
    for (int d = 0; d < 64; ++d) {
        float4 q4 = *(const float4*)&Ql[d][ty * 4];
        float4 k4 = *(const float4*)&Kl[d][tx * 4];
        float qv[4] = {q4.x, q4.y, q4.z, q4.w};
        float kv[4] = {k4.x, k4.y, k4.z, k4.w};
        #pragma unroll
        for (int a = 0; a < 4; ++a)
            #pragma unroll
            for (int b = 0; b < 4; ++b) acc[a][b] += qv[a] * kv[b];
    }
    #pragma unroll
    for (int a = 0; a < 4; ++a) {
        float4 o;
        o.x = acc[a][0] * 0.125f; o.y = acc[a][1] * 0.125f;
        o.z = acc[a][2] * 0.125f; o.w = acc[a][3] * 0.125f;
        *(float4*)&aff[(((size_t)(c * GG + g)) * NT + i0 + ty * 4 + a) * NT + j0 + tx * 4] = o;
    }
}

// ---------------------------------------------------------------------------
// K3 v2: fused dense + top-10 scan, small-footprint for occupancy.
//   Block = (256-j chunk, 8-i tile, c); 8 subtiles of 32 j.
//   Phase G (256 thr): thread=(i, j) -> 1 pe row, 16-g GEMM -> log -> LDS.
//   Phase S (256 thr): thread=(i, g, half16) scans 16 j, top-10 in regs.
//   LDS ~22KB (7 blocks/CU), VGPR capped ~102 (5 waves/SIMD).
//   Scan order within chunk = j ascending (identical to R6 -> same absmax).
// ---------------------------------------------------------------------------
__global__ __launch_bounds__(256, 5) void k3_scan(
    const float* __restrict__ pe, const float* __restrict__ iou,
    const float* __restrict__ WGw, const float* __restrict__ WGb,
    const float* __restrict__ aff,
    float* __restrict__ cv, int* __restrict__ ci)
{
    const int ch = blockIdx.x;   // 0..3
    const int it = blockIdx.y;   // 0..127
    const int c  = blockIdx.z;
    const int i0 = it * 8;

    __shared__ float wgw[16][64];      // 4KB, broadcast reads
    __shared__ float wgb_s[16];
    __shared__ float wgl[8][16][33];   // [i][g][j(32)+1] 16.9KB, 2-way banks
    __shared__ float ios[8][33];       // log_iou [i][j], bcast/2-way

    const int t = threadIdx.x;
    ((float4*)&wgw[0][0])[t] = ((const float4*)WGw)[t];   // 1024 floats
    if (t < 16) wgb_s[t] = WGb[t];
    __syncthreads();

    const int p_i = t >> 5, jq = t & 31;                       // phase-G map
    const int s_i = t >> 5, s_g = (t >> 1) & 15, s_h = t & 1;  // phase-S map

    float tv[10]; int tidx[10];
    #pragma unroll
    for (int q = 0; q < 10; ++q) { tv[q] = NEG_BIG; tidx[q] = 0; }

    for (int s = 0; s < 8; ++s) {
        const int j0 = ch * 256 + s * 32;
        // ---- phase G: one pe row per thread, 16-g accumulate ----
        float acc[16];
        #pragma unroll
        for (int g = 0; g < 16; ++g) acc[g] = wgb_s[g];
        const float* pr = &pe[(((size_t)c * NT + (i0 + p_i)) * NT + (j0 + jq)) * 64];
        #pragma unroll 1
        for (int db = 0; db < 64; db += 16) {
            float4 pa[4];
            #pragma unroll
            for (int k = 0; k < 4; ++k) pa[k] = *(const float4*)&pr[db + 4 * k];
            #pragma unroll
            for (int g = 0; g < 16; ++g) {
                #pragma unroll
                for (int k = 0; k < 4; ++k) {
                    float4 w = *(const float4*)&wgw[g][db + 4 * k];
                    acc[g] += pa[k].x * w.x + pa[k].y * w.y + pa[k].z * w.z + pa[k].w * w.w;
                }
            }
        }
        {
            const float ia = iou[((size_t)c * NT + (i0 + p_i)) * NT + j0 + jq];
            ios[p_i][jq] = (ia >= 1e-6f) ? 0.f : LOG1E6;
        }
        #pragma unroll
        for (int g = 0; g < 16; ++g)
            wgl[p_i][g][jq] = (acc[g] > 1e-6f) ? __logf(acc[g]) : LOG1E6;
        __syncthreads();
        // ---- phase S: 16 j per thread ----
        {
            const float* ar = &aff[(((size_t)(c * GG + s_g)) * NT + (i0 + s_i)) * NT + j0 + s_h * 16];
            const float* wl = &wgl[s_i][s_g][s_h * 16];
            const float* il = &ios[s_i][s_h * 16];
            #pragma unroll
            for (int j4 = 0; j4 < 16; j4 += 4) {
                float4 a4 = *(const float4*)&ar[j4];
                float av[4] = {a4.x, a4.y, a4.z, a4.w};
                #pragma unroll
                for (int q = 0; q < 4; ++q) {
                    const float val = wl[j4 + q] + av[q] + il[j4 + q];
                    if (val > tv[0]) {
                        const int ix = j0 + s_h * 16 + j4 + q;
                        #pragma unroll
                        for (int sl = 0; sl < 10; ++sl) {
                            const bool up   = (sl < 9) ? (val > tv[sl + 1]) : false;
                            const bool here = (val > tv[sl]);
                            const float ntv = up ? tv[sl + 1] : (here ? val : tv[sl]);
                            const int   nti = up ? tidx[sl + 1] : (here ? ix : tidx[sl]);
                            tv[sl] = ntv; tidx[sl] = nti;
                        }
                    }
                }
            }
        }
        __syncthreads();
    }

    // ---- merge s_h=0/1 lists via LDS scratch (2560 words, reuse wgl) ----
    float* mv = &wgl[0][0][0];
    int*   mi = (int*)(mv + 1280);
    const int pair = t >> 1;
    if (s_h == 1) {
        #pragma unroll
        for (int q = 0; q < 10; ++q) { mv[pair * 10 + q] = tv[q]; mi[pair * 10 + q] = tidx[q]; }
    }
    __syncthreads();
    if (s_h == 0) {
        for (int q = 9; q >= 0; --q) {
            const float val = mv[pair * 10 + q];
            const int   ix  = mi[pair * 10 + q];
            if (val > tv[0]) {
                #pragma unroll
                for (int sl = 0; sl < 10; ++sl) {
                    const bool up   = (sl < 9) ? (val > tv[sl + 1]) : false;
                    const bool here = (val > tv[sl]);
                    const float ntv = up ? tv[sl + 1] : (here ? val : tv[sl]);
                    const int   nti = up ? tidx[sl + 1] : (here ? ix : tidx[sl]);
                    tv[sl] = ntv; tidx[sl] = nti;
                }
            }
        }
        const size_t base = ((((size_t)c * NT + (i0 + s_i)) * GG + s_g) * 4 + ch) * 10;
        #pragma unroll
        for (int q = 0; q < 10; ++q) { cv[base + q] = tv[q]; ci[base + q] = tidx[q]; }
    }
}

// ---------------------------------------------------------------------------
// K2b2: one 64-lane wave per (c,i,g) row; merge 4x10 ascending chunk lists
//       (scanned descending), softmax, coalesced V-gather.
// ---------------------------------------------------------------------------
__global__ __launch_bounds__(256) void k2b2_fin(
    const float* __restrict__ cv, const int* __restrict__ ci,
    const float* __restrict__ V, float* __restrict__ y)
{
    const int w    = (blockIdx.x << 2) + (threadIdx.x >> 6);
    const int lane = threadIdx.x & 63;
    const int c = w >> 14;
    const int i = (w >> 4) & (NT - 1);
    const int g = w & 15;

    float tv[10]; int tidx[10];
    #pragma unroll
    for (int q = 0; q < 10; ++q) { tv[q] = NEG_BIG; tidx[q] = 0; }

    const size_t base = (size_t)w * 40;
    for (int chn = 0; chn < 4; ++chn) {
        const float* cvp = &cv[base + chn * 10];
        const int*   cip = &ci[base + chn * 10];
        for (int q = 9; q >= 0; --q) {
            const float val = cvp[q];
            const int   ix  = cip[q];
            if (val > tv[0]) {
                #pragma unroll
                for (int sl = 0; sl < 10; ++sl) {
                    const bool up   = (sl < 9) ? (val > tv[sl + 1]) : false;
                    const bool here = (val > tv[sl]);
                    const float ntv = up ? tv[sl + 1] : (here ? val : tv[sl]);
                    const int   nti = up ? tidx[sl + 1] : (here ? ix : tidx[sl]);
                    tv[sl] = ntv; tidx[sl] = nti;
                }
            }
        }
    }
    const float m = tv[9];
    float wgt[10]; float sm = 0.f;
    #pragma unroll
    for (int q = 0; q < 10; ++q) { wgt[q] = __expf(tv[q] - m); sm += wgt[q]; }
    const float inv = 1.f / sm;
    float o = 0.f;
    #pragma unroll
    for (int q = 0; q < 10; ++q)
        o += (wgt[q] * inv) * V[((size_t)(c * NT + tidx[q])) * DD + g * 64 + lane];
    y[((size_t)i * CD + c) * DD + g * 64 + lane] = o;
}

extern "C" void kernel_launch(void* const* d_in, const int* in_sizes, int n_in,
                              void* d_out, int out_size, void* d_ws, size_t ws_size,
                              hipStream_t stream) {
    (void)in_sizes; (void)n_in; (void)out_size; (void)ws_size;
    const float* f_a = (const float*)d_in[0];
    const float* pe  = (const float*)d_in[1];
    const float* iou = (const float*)d_in[2];
    const float* WGw = (const float*)d_in[3];
    const float* WGb = (const float*)d_in[4];
    const float* WKw = (const float*)d_in[5];
    const float* WKb = (const float*)d_in[6];
    const float* WQw = (const float*)d_in[7];
    const float* WQb = (const float*)d_in[8];
    const float* Cw  = (const float*)d_in[9];
    const float* Cb  = (const float*)d_in[10];
    float* yout = (float*)d_out;

    // ws floats: Q [2^21] | K [2^21] | V [2^21] | aff [2^25]  (~159.4 MB)
    // cv overlays Q, ci overlays K (dead after k2a).
    float* ws  = (float*)d_ws;
    float* Q   = ws;
    float* Kp  = ws + (1u << 21);
    float* V   = ws + (2u << 21);
    float* aff = ws + (3u << 21);
    float* cv  = ws;
    int*   ci  = (int*)(ws + (1u << 21));

    k1_proj<<<dim3(16, 16, 3), 256, 0, stream>>>(f_a, WQw, WQb, WKw, WKb, Cw, Cb, Q, Kp, V);
    k2a_aff<<<dim3(16, 16, 32), 256, 0, stream>>>(Q, Kp, aff);
    k3_scan<<<dim3(4, 128, 2), 256, 0, stream>>>(pe, iou, WGw, WGb, aff, cv, ci);
    k2b2_fin<<<8192, 256, 0, stream>>>(cv, ci, V, yout);
}

// Round 8
// 566.935 us; speedup vs baseline: 1.4736x; 1.0303x over previous
//
#include <hip/hip_runtime.h>
#include <math.h>

#define NT 1024
#define CD 2
#define DD 1024
#define GG 16
#define LOG1E6 -13.8155105579642740f
#define NEG_BIG -1e30f

// ---------------------------------------------------------------------------
// K1: fp32 GEMM  P_z[r][e] = sum_d A[r][d] * W_z[e][d] + b_z[e]
//     tile 128 rows x 64 cols, BK=32, 256 threads, 8x4 micro-tile
//     (fp32 VALU on purpose: split-bf16 MFMA's ~1e-5 aff error widens the
//      top-k tie window 10x and flips ranks -> 0.145 absmax in R5.)
// ---------------------------------------------------------------------------
__global__ __launch_bounds__(256) void k1_proj(
    const float* __restrict__ fa,
    const float* __restrict__ Wq, const float* __restrict__ bq,
    const float* __restrict__ Wk, const float* __restrict__ bk,
    const float* __restrict__ Wc, const float* __restrict__ bc,
    float* __restrict__ Qo, float* __restrict__ Ko, float* __restrict__ Vo)
{
    const int et = blockIdx.x, rt = blockIdx.y, z = blockIdx.z;
    const float* W  = (z == 0) ? Wq : (z == 1) ? Wk : Wc;
    const float* bb = (z == 0) ? bq : (z == 1) ? bk : bc;
    float* Out      = (z == 0) ? Qo : (z == 1) ? Ko : Vo;

    __shared__ float Al[32][132];
    __shared__ float Wl[32][68];

    const int t  = threadIdx.x;
    const int tx = t & 15, ty = t >> 4;
    const int dd = t & 7,  rr = t >> 3;
    const int r0 = rt * 128, e0 = et * 64;

    float acc[8][4];
    #pragma unroll
    for (int a = 0; a < 8; ++a)
        #pragma unroll
        for (int b = 0; b < 4; ++b) acc[a][b] = 0.f;

    for (int kt = 0; kt < 32; ++kt) {
        const int db = kt * 32 + dd * 4;
        #pragma unroll
        for (int p = 0; p < 4; ++p) {
            const int row = rr + p * 32;
            const int r = r0 + row;
            const int n = r & (NT - 1), c = r >> 10;
            float4 a4 = *(const float4*)&fa[((size_t)(n * CD + c)) * DD + db];
            Al[dd*4+0][row] = a4.x; Al[dd*4+1][row] = a4.y;
            Al[dd*4+2][row] = a4.z; Al[dd*4+3][row] = a4.w;
        }
        #pragma unroll
        for (int p = 0; p < 2; ++p) {
            const int erow = rr + p * 32;
            float4 w4 = *(const float4*)&W[((size_t)(e0 + erow)) * DD + db];
            Wl[dd*4+0][erow] = w4.x; Wl[dd*4+1][erow] = w4.y;
            Wl[dd*4+2][erow] = w4.z; Wl[dd*4+3][erow] = w4.w;
        }
        __syncthreads();
        #pragma unroll 4
        for (int d = 0; d < 32; ++d) {
            float4 a0 = *(const float4*)&Al[d][ty * 8];
            float4 a1 = *(const float4*)&Al[d][ty * 8 + 4];
            float4 w4 = *(const float4*)&Wl[d][tx * 4];
            float av[8] = {a0.x, a0.y, a0.z, a0.w, a1.x, a1.y, a1.z, a1.w};
            float wv[4] = {w4.x, w4.y, w4.z, w4.w};
            #pragma unroll
            for (int a = 0; a < 8; ++a)
                #pragma unroll
                for (int b = 0; b < 4; ++b) acc[a][b] += av[a] * wv[b];
        }
        __syncthreads();
    }
    float4 b4 = *(const float4*)&bb[e0 + tx * 4];
    #pragma unroll
    for (int a = 0; a < 8; ++a) {
        float4 o;
        o.x = acc[a][0] + b4.x; o.y = acc[a][1] + b4.y;
        o.z = acc[a][2] + b4.z; o.w = acc[a][3] + b4.w;
        *(float4*)&Out[((size_t)(r0 + ty * 8 + a)) * DD + e0 + tx * 4] = o;
    }
}

// ---------------------------------------------------------------------------
// K2a: aff[c][g][i][j] = (sum_d Q[c,i,g*64+d] * K[c,j,g*64+d]) / 8   (fp32)
// ---------------------------------------------------------------------------
__global__ __launch_bounds__(256) void k2a_aff(
    const float* __restrict__ Q, const float* __restrict__ Km,
    float* __restrict__ aff)
{
    const int jt = blockIdx.x, it = blockIdx.y, cg = blockIdx.z;
    const int c = cg >> 4, g = cg & 15;
    __shared__ float Ql[64][68];
    __shared__ float Kl[64][68];
    const int t = threadIdx.x;
    const int dd = t & 15, rr = t >> 4;
    const int i0 = it * 64, j0 = jt * 64;
    #pragma unroll
    for (int p = 0; p < 4; ++p) {
        const int row = rr + p * 16;
        float4 q4 = *(const float4*)&Q[((size_t)(c * NT + i0 + row)) * DD + g * 64 + dd * 4];
        Ql[dd*4+0][row] = q4.x; Ql[dd*4+1][row] = q4.y;
        Ql[dd*4+2][row] = q4.z; Ql[dd*4+3][row] = q4.w;
        float4 k4 = *(const float4*)&Km[((size_t)(c * NT + j0 + row)) * DD + g * 64 + dd * 4];
        Kl[dd*4+0][row] = k4.x; Kl[dd*4+1][row] = k4.y;
        Kl[dd*4+2][row] = k4.z; Kl[dd*4+3][row] = k4.w;
    }
    __syncthreads();
    const int tx = t & 15, ty = t >> 4;
    float acc[4][4];
    #pragma unroll
    for (int a = 0; a < 4; ++a)
        #pragma unroll
        for (int b = 0; b < 4; ++b) acc[a][b] = 0.f;
    #pragma unroll 8
    for (int d = 0; d < 64; ++d) {
        float4 q4 = *(const float4*)&Ql[d][ty * 4];
        float4 k4 = *(const float4*)&Kl[d][tx * 4];
        float qv[4] = {q4.x, q4.y, q4.z, q4.w};
        float kv[4] = {k4.x, k4.y, k4.z, k4.w};
        #pragma unroll
        for (int a = 0; a < 4; ++a)
            #pragma unroll
            for (int b = 0; b < 4; ++b) acc[a][b] += qv[a] * kv[b];
    }
    #pragma unroll
    for (int a = 0; a < 4; ++a) {
        float4 o;
        o.x = acc[a][0] * 0.125f; o.y = acc[a][1] * 0.125f;
        o.z = acc[a][2] * 0.125f; o.w = acc[a][3] * 0.125f;
        *(float4*)&aff[(((size_t)(c * GG + g)) * NT + i0 + ty * 4 + a) * NT + j0 + tx * 4] = o;
    }
}

// ---------------------------------------------------------------------------
// K3 v3: fused dense + top-10 scan, SGPR-operand GEMM.
//   wgw is wave-uniform -> read directly from global with uniform indices;
//   compiler scalarizes to s_load + SGPR-src v_fma (4KB lives in sL1).
//   Inner loop has ZERO LDS traffic (R7 was LDS-pipe-bound: 1 ds_read_b128
//   per 4 FMAs on one LDS pipe/CU).
//   Block = (256-j chunk, 8-i tile, c); 8 subtiles of 32 j.
//   Phase G: thread=(i,j) computes 16 g -> log -> wgl LDS.
//   Phase S: thread=(i,g,half16) scans 16 j, top-10 in regs.
// ---------------------------------------------------------------------------
__global__ __launch_bounds__(256, 6) void k3_scan(
    const float* __restrict__ pe, const float* __restrict__ iou,
    const float* __restrict__ WGw, const float* __restrict__ WGb,
    const float* __restrict__ aff,
    float* __restrict__ cv, int* __restrict__ ci)
{
    const int ch = blockIdx.x;   // 0..3
    const int it = blockIdx.y;   // 0..127
    const int c  = blockIdx.z;
    const int i0 = it * 8;

    __shared__ float wgl[8][16][33];   // [i][g][j(32)+1] 16.9KB, <=2-way banks
    __shared__ float ios[8][33];       // log_iou [i][j]

    const int t = threadIdx.x;
    const int p_i = t >> 5, jq = t & 31;                       // phase-G map
    const int s_i = t >> 5, s_g = (t >> 1) & 15, s_h = t & 1;  // phase-S map

    float tv[10]; int tidx[10];
    #pragma unroll
    for (int q = 0; q < 10; ++q) { tv[q] = NEG_BIG; tidx[q] = 0; }

    for (int s = 0; s < 8; ++s) {
        const int j0 = ch * 256 + s * 32;
        // ---- phase G: one pe row per thread; wgw via scalar loads ----
        float acc[16];
        #pragma unroll
        for (int g = 0; g < 16; ++g) acc[g] = WGb[g];   // uniform -> s_load
        const float* pr = &pe[(((size_t)c * NT + (i0 + p_i)) * NT + (j0 + jq)) * 64];
        #pragma unroll 1
        for (int db = 0; db < 64; db += 16) {
            float4 pa[4];
            #pragma unroll
            for (int k = 0; k < 4; ++k) pa[k] = *(const float4*)&pr[db + 4 * k];
            #pragma unroll
            for (int g = 0; g < 16; ++g) {
                #pragma unroll
                for (int k = 0; k < 4; ++k) {
                    // uniform address (g,db,k wave-invariant) -> s_load_dwordx4,
                    // FMA uses SGPR src1 (one SGPR operand per VALU inst: legal)
                    float4 w = *(const float4*)&WGw[g * 64 + db + 4 * k];
                    acc[g] += pa[k].x * w.x + pa[k].y * w.y + pa[k].z * w.z + pa[k].w * w.w;
                }
            }
        }
        {
            const float ia = iou[((size_t)c * NT + (i0 + p_i)) * NT + j0 + jq];
            ios[p_i][jq] = (ia >= 1e-6f) ? 0.f : LOG1E6;
        }
        #pragma unroll
        for (int g = 0; g < 16; ++g)
            wgl[p_i][g][jq] = (acc[g] > 1e-6f) ? __logf(acc[g]) : LOG1E6;
        __syncthreads();
        // ---- phase S: 16 j per thread ----
        {
            const float* ar = &aff[(((size_t)(c * GG + s_g)) * NT + (i0 + s_i)) * NT + j0 + s_h * 16];
            const float* wl = &wgl[s_i][s_g][s_h * 16];
            const float* il = &ios[s_i][s_h * 16];
            #pragma unroll
            for (int j4 = 0; j4 < 16; j4 += 4) {
                float4 a4 = *(const float4*)&ar[j4];
                float av[4] = {a4.x, a4.y, a4.z, a4.w};
                #pragma unroll
                for (int q = 0; q < 4; ++q) {
                    const float val = wl[j4 + q] + av[q] + il[j4 + q];
                    if (val > tv[0]) {
                        const int ix = j0 + s_h * 16 + j4 + q;
                        #pragma unroll
                        for (int sl = 0; sl < 10; ++sl) {
                            const bool up   = (sl < 9) ? (val > tv[sl + 1]) : false;
                            const bool here = (val > tv[sl]);
                            const float ntv = up ? tv[sl + 1] : (here ? val : tv[sl]);
                            const int   nti = up ? tidx[sl + 1] : (here ? ix : tidx[sl]);
                            tv[sl] = ntv; tidx[sl] = nti;
                        }
                    }
                }
            }
        }
        __syncthreads();
    }

    // ---- merge s_h=0/1 lists via LDS scratch (2560 words, reuse wgl) ----
    float* mv = &wgl[0][0][0];
    int*   mi = (int*)(mv + 1280);
    const int pair = t >> 1;
    if (s_h == 1) {
        #pragma unroll
        for (int q = 0; q < 10; ++q) { mv[pair * 10 + q] = tv[q]; mi[pair * 10 + q] = tidx[q]; }
    }
    __syncthreads();
    if (s_h == 0) {
        for (int q = 9; q >= 0; --q) {
            const float val = mv[pair * 10 + q];
            const int   ix  = mi[pair * 10 + q];
            if (val > tv[0]) {
                #pragma unroll
                for (int sl = 0; sl < 10; ++sl) {
                    const bool up   = (sl < 9) ? (val > tv[sl + 1]) : false;
                    const bool here = (val > tv[sl]);
                    const float ntv = up ? tv[sl + 1] : (here ? val : tv[sl]);
                    const int   nti = up ? tidx[sl + 1] : (here ? ix : tidx[sl]);
                    tv[sl] = ntv; tidx[sl] = nti;
                }
            }
        }
        const size_t base = ((((size_t)c * NT + (i0 + s_i)) * GG + s_g) * 4 + ch) * 10;
        #pragma unroll
        for (int q = 0; q < 10; ++q) { cv[base + q] = tv[q]; ci[base + q] = tidx[q]; }
    }
}

// ---------------------------------------------------------------------------
// K2b2: one 64-lane wave per (c,i,g) row; merge 4x10 ascending chunk lists
//       (scanned descending), softmax, coalesced V-gather.
// ---------------------------------------------------------------------------
__global__ __launch_bounds__(256) void k2b2_fin(
    const float* __restrict__ cv, const int* __restrict__ ci,
    const float* __restrict__ V, float* __restrict__ y)
{
    const int w    = (blockIdx.x << 2) + (threadIdx.x >> 6);
    const int lane = threadIdx.x & 63;
    const int c = w >> 14;
    const int i = (w >> 4) & (NT - 1);
    const int g = w & 15;

    float tv[10]; int tidx[10];
    #pragma unroll
    for (int q = 0; q < 10; ++q) { tv[q] = NEG_BIG; tidx[q] = 0; }

    const size_t base = (size_t)w * 40;
    for (int chn = 0; chn < 4; ++chn) {
        const float* cvp = &cv[base + chn * 10];
        const int*   cip = &ci[base + chn * 10];
        for (int q = 9; q >= 0; --q) {
            const float val = cvp[q];
            const int   ix  = cip[q];
            if (val > tv[0]) {
                #pragma unroll
                for (int sl = 0; sl < 10; ++sl) {
                    const bool up   = (sl < 9) ? (val > tv[sl + 1]) : false;
                    const bool here = (val > tv[sl]);
                    const float ntv = up ? tv[sl + 1] : (here ? val : tv[sl]);
                    const int   nti = up ? tidx[sl + 1] : (here ? ix : tidx[sl]);
                    tv[sl] = ntv; tidx[sl] = nti;
                }
            }
        }
    }
    const float m = tv[9];
    float wgt[10]; float sm = 0.f;
    #pragma unroll
    for (int q = 0; q < 10; ++q) { wgt[q] = __expf(tv[q] - m); sm += wgt[q]; }
    const float inv = 1.f / sm;
    float o = 0.f;
    #pragma unroll
    for (int q = 0; q < 10; ++q)
        o += (wgt[q] * inv) * V[((size_t)(c * NT + tidx[q])) * DD + g * 64 + lane];
    y[((size_t)i * CD + c) * DD + g * 64 + lane] = o;
}

extern "C" void kernel_launch(void* const* d_in, const int* in_sizes, int n_in,
                              void* d_out, int out_size, void* d_ws, size_t ws_size,
                              hipStream_t stream) {
    (void)in_sizes; (void)n_in; (void)out_size; (void)ws_size;
    const float* f_a = (const float*)d_in[0];
    const float* pe  = (const float*)d_in[1];
    const float* iou = (const float*)d_in[2];
    const float* WGw = (const float*)d_in[3];
    const float* WGb = (const float*)d_in[4];
    const float* WKw = (const float*)d_in[5];
    const float* WKb = (const float*)d_in[6];
    const float* WQw = (const float*)d_in[7];
    const float* WQb = (const float*)d_in[8];
    const float* Cw  = (const float*)d_in[9];
    const float* Cb  = (const float*)d_in[10];
    float* yout = (float*)d_out;

    // ws floats: Q [2^21] | K [2^21] | V [2^21] | aff [2^25]  (~159.4 MB)
    // cv overlays Q, ci overlays K (dead after k2a).
    float* ws  = (float*)d_ws;
    float* Q   = ws;
    float* Kp  = ws + (1u << 21);
    float* V   = ws + (2u << 21);
    float* aff = ws + (3u << 21);
    float* cv  = ws;
    int*   ci  = (int*)(ws + (1u << 21));

    k1_proj<<<dim3(16, 16, 3), 256, 0, stream>>>(f_a, WQw, WQb, WKw, WKb, Cw, Cb, Q, Kp, V);
    k2a_aff<<<dim3(16, 16, 32), 256, 0, stream>>>(Q, Kp, aff);
    k3_scan<<<dim3(4, 128, 2), 256, 0, stream>>>(pe, iou, WGw, WGb, aff, cv, ci);
    k2b2_fin<<<8192, 256, 0, stream>>>(cv, ci, V, yout);
}

// Round 9
// 512.491 us; speedup vs baseline: 1.6301x; 1.1062x over previous
//
#include <hip/hip_runtime.h>
#include <math.h>

#define NT 1024
#define CD 2
#define DD 1024
#define GG 16
#define LOG1E6 -13.8155105579642740f
#define NEG_BIG -1e30f

typedef short bf16x8 __attribute__((ext_vector_type(8)));
typedef float f32x4  __attribute__((ext_vector_type(4)));

__device__ __forceinline__ unsigned short bf16_rne(float x) {
    unsigned int u = __float_as_uint(x);
    unsigned int r = (u + 0x7fffu + ((u >> 16) & 1u)) >> 16;
    return (unsigned short)r;
}

// 3-way bf16 split of 8 fp32 values: x = h + m + l (24 mantissa bits kept).
__device__ __forceinline__ void split3_8(const float* v, bf16x8& h, bf16x8& m, bf16x8& l) {
    #pragma unroll
    for (int e = 0; e < 8; ++e) {
        const float x = v[e];
        const unsigned short hb = bf16_rne(x);
        const float hf = __uint_as_float((unsigned int)hb << 16);
        const float r1 = x - hf;                   // exact (Sterbenz-ish)
        const unsigned short mb = bf16_rne(r1);
        const float mf = __uint_as_float((unsigned int)mb << 16);
        const float r2 = r1 - mf;                  // exact
        const unsigned short lb = bf16_rne(r2);
        h[e] = (short)hb; m[e] = (short)mb; l[e] = (short)lb;
    }
}

// ---------------------------------------------------------------------------
// K1: fp32 GEMM  P_z[r][e] = sum_d A[r][d] * W_z[e][d] + b_z[e]
//     tile 128 rows x 64 cols, BK=32, 256 threads, 8x4 micro-tile
// ---------------------------------------------------------------------------
__global__ __launch_bounds__(256) void k1_proj(
    const float* __restrict__ fa,
    const float* __restrict__ Wq, const float* __restrict__ bq,
    const float* __restrict__ Wk, const float* __restrict__ bk,
    const float* __restrict__ Wc, const float* __restrict__ bc,
    float* __restrict__ Qo, float* __restrict__ Ko, float* __restrict__ Vo)
{
    const int et = blockIdx.x, rt = blockIdx.y, z = blockIdx.z;
    const float* W  = (z == 0) ? Wq : (z == 1) ? Wk : Wc;
    const float* bb = (z == 0) ? bq : (z == 1) ? bk : bc;
    float* Out      = (z == 0) ? Qo : (z == 1) ? Ko : Vo;

    __shared__ float Al[32][132];
    __shared__ float Wl[32][68];

    const int t  = threadIdx.x;
    const int tx = t & 15, ty = t >> 4;
    const int dd = t & 7,  rr = t >> 3;
    const int r0 = rt * 128, e0 = et * 64;

    float acc[8][4];
    #pragma unroll
    for (int a = 0; a < 8; ++a)
        #pragma unroll
        for (int b = 0; b < 4; ++b) acc[a][b] = 0.f;

    for (int kt = 0; kt < 32; ++kt) {
        const int db = kt * 32 + dd * 4;
        #pragma unroll
        for (int p = 0; p < 4; ++p) {
            const int row = rr + p * 32;
            const int r = r0 + row;
            const int n = r & (NT - 1), c = r >> 10;
            float4 a4 = *(const float4*)&fa[((size_t)(n * CD + c)) * DD + db];
            Al[dd*4+0][row] = a4.x; Al[dd*4+1][row] = a4.y;
            Al[dd*4+2][row] = a4.z; Al[dd*4+3][row] = a4.w;
        }
        #pragma unroll
        for (int p = 0; p < 2; ++p) {
            const int erow = rr + p * 32;
            float4 w4 = *(const float4*)&W[((size_t)(e0 + erow)) * DD + db];
            Wl[dd*4+0][erow] = w4.x; Wl[dd*4+1][erow] = w4.y;
            Wl[dd*4+2][erow] = w4.z; Wl[dd*4+3][erow] = w4.w;
        }
        __syncthreads();
        #pragma unroll 4
        for (int d = 0; d < 32; ++d) {
            float4 a0 = *(const float4*)&Al[d][ty * 8];
            float4 a1 = *(const float4*)&Al[d][ty * 8 + 4];
            float4 w4 = *(const float4*)&Wl[d][tx * 4];
            float av[8] = {a0.x, a0.y, a0.z, a0.w, a1.x, a1.y, a1.z, a1.w};
            float wv[4] = {w4.x, w4.y, w4.z, w4.w};
            #pragma unroll
            for (int a = 0; a < 8; ++a)
                #pragma unroll
                for (int b = 0; b < 4; ++b) acc[a][b] += av[a] * wv[b];
        }
        __syncthreads();
    }
    float4 b4 = *(const float4*)&bb[e0 + tx * 4];
    #pragma unroll
    for (int a = 0; a < 8; ++a) {
        float4 o;
        o.x = acc[a][0] + b4.x; o.y = acc[a][1] + b4.y;
        o.z = acc[a][2] + b4.z; o.w = acc[a][3] + b4.w;
        *(float4*)&Out[((size_t)(r0 + ty * 8 + a)) * DD + e0 + tx * 4] = o;
    }
}

// ---------------------------------------------------------------------------
// K2a: aff[c][g][i][j] = (sum_d Q[c,i,g*64+d] * K[c,j,g*64+d]) / 8   (fp32)
// ---------------------------------------------------------------------------
__global__ __launch_bounds__(256) void k2a_aff(
    const float* __restrict__ Q, const float* __restrict__ Km,
    float* __restrict__ aff)
{
    const int jt = blockIdx.x, it = blockIdx.y, cg = blockIdx.z;
    const int c = cg >> 4, g = cg & 15;
    __shared__ float Ql[64][68];
    __shared__ float Kl[64][68];
    const int t = threadIdx.x;
    const int dd = t & 15, rr = t >> 4;
    const int i0 = it * 64, j0 = jt * 64;
    #pragma unroll
    for (int p = 0; p < 4; ++p) {
        const int row = rr + p * 16;
        float4 q4 = *(const float4*)&Q[((size_t)(c * NT + i0 + row)) * DD + g * 64 + dd * 4];
        Ql[dd*4+0][row] = q4.x; Ql[dd*4+1][row] = q4.y;
        Ql[dd*4+2][row] = q4.z; Ql[dd*4+3][row] = q4.w;
        float4 k4 = *(const float4*)&Km[((size_t)(c * NT + j0 + row)) * DD + g * 64 + dd * 4];
        Kl[dd*4+0][row] = k4.x; Kl[dd*4+1][row] = k4.y;
        Kl[dd*4+2][row] = k4.z; Kl[dd*4+3][row] = k4.w;
    }
    __syncthreads();
    const int tx = t & 15, ty = t >> 4;
    float acc[4][4];
    #pragma unroll
    for (int a = 0; a < 4; ++a)
        #pragma unroll
        for (int b = 0; b < 4; ++b) acc[a][b] = 0.f;
    #pragma unroll 8
    for (int d = 0; d < 64; ++d) {
        float4 q4 = *(const float4*)&Ql[d][ty * 4];
        float4 k4 = *(const float4*)&Kl[d][tx * 4];
        float qv[4] = {q4.x, q4.y, q4.z, q4.w};
        float kv[4] = {k4.x, k4.y, k4.z, k4.w};
        #pragma unroll
        for (int a = 0; a < 4; ++a)
            #pragma unroll
            for (int b = 0; b < 4; ++b) acc[a][b] += qv[a] * kv[b];
    }
    #pragma unroll
    for (int a = 0; a < 4; ++a) {
        float4 o;
        o.x = acc[a][0] * 0.125f; o.y = acc[a][1] * 0.125f;
        o.z = acc[a][2] * 0.125f; o.w = acc[a][3] * 0.125f;
        *(float4*)&aff[(((size_t)(c * GG + g)) * NT + i0 + ty * 4 + a) * NT + j0 + tx * 4] = o;
    }
}

// ---------------------------------------------------------------------------
// K3 v4: fused dense + top-10 scan; phase-G on the MATRIX pipe.
//   w_g GEMM (M=rows(i,j), N=16 g, K=64) via mfma_f32_16x16x32_bf16 with
//   6-term 3-way-split (hh,hm,mh,mm,hl,lh): error ~2^-26 rel = fp32 class
//   (R5's 2-term split at 2^-16 flipped top-k; this does not).
//   B (WGw) lives in 24 VGPR-resident bf16x8 frags; A (pe) global->regs->
//   split: ZERO LDS / scalar traffic in the GEMM (R7 LDS-pipe-bound,
//   R8 scalar-pipe-bound).
//   Block = (256-j chunk, 8-i tile, c); 8 subtiles of (8i x 32j).
//   Per subtile: wave w computes row-tiles 4w..4w+3 (16 rows each);
//   C frag col=lane&15 (g), row=(lane>>4)*4+q -> relu/clip/log -> wgl.
//   Phase S (unchanged from R8): thread=(i,g,half16) scans 16 j.
// ---------------------------------------------------------------------------
__global__ __launch_bounds__(256, 4) void k3_scan(
    const float* __restrict__ pe, const float* __restrict__ iou,
    const float* __restrict__ WGw, const float* __restrict__ WGb,
    const float* __restrict__ aff,
    float* __restrict__ cv, int* __restrict__ ci)
{
    const int ch = blockIdx.x;   // 0..3
    const int it = blockIdx.y;   // 0..127
    const int c  = blockIdx.z;
    const int i0 = it * 8;

    __shared__ float wgl[8][16][33];   // [i][g][j(32)+1]
    __shared__ float ios[8][33];       // log_iou [i][j]

    const int t = threadIdx.x;
    const int wave = t >> 6, lane = t & 63;
    const int lg = lane & 15, lk = lane >> 4;                  // frag maps
    const int p_i = t >> 5, jq = t & 31;                       // ios map
    const int s_i = t >> 5, s_g = (t >> 1) & 15, s_h = t & 1;  // phase-S map

    // B-frags: lane holds WGw[g=lg][k = kp*32 + lk*8 + e], split 3-way.
    bf16x8 bh[2], bm[2], bl[2];
    #pragma unroll
    for (int kp = 0; kp < 2; ++kp) {
        float w8[8];
        float4 w0 = *(const float4*)&WGw[lg * 64 + kp * 32 + lk * 8];
        float4 w1 = *(const float4*)&WGw[lg * 64 + kp * 32 + lk * 8 + 4];
        w8[0]=w0.x; w8[1]=w0.y; w8[2]=w0.z; w8[3]=w0.w;
        w8[4]=w1.x; w8[5]=w1.y; w8[6]=w1.z; w8[7]=w1.w;
        split3_8(w8, bh[kp], bm[kp], bl[kp]);
    }
    const float bias = WGb[lg];

    float tv[10]; int tidx[10];
    #pragma unroll
    for (int q = 0; q < 10; ++q) { tv[q] = NEG_BIG; tidx[q] = 0; }

    for (int s = 0; s < 8; ++s) {
        const int j0 = ch * 256 + s * 32;
        // ---- ios staging (as R8) ----
        {
            const float ia = iou[((size_t)c * NT + (i0 + p_i)) * NT + j0 + jq];
            ios[p_i][jq] = (ia >= 1e-6f) ? 0.f : LOG1E6;
        }
        // ---- phase G: 4 row-tiles per wave, 12 MFMAs each ----
        #pragma unroll 1
        for (int rtt = 0; rtt < 4; ++rtt) {
            const int rt = wave * 4 + rtt;     // 0..15
            const int ib = rt >> 1;            // i in tile
            const int jb = (rt & 1) * 16;      // j base in 32
            const float* pr = &pe[(((size_t)c * NT + (i0 + ib)) * NT + (j0 + jb + lg)) * 64];
            f32x4 acc = {0.f, 0.f, 0.f, 0.f};
            #pragma unroll
            for (int kp = 0; kp < 2; ++kp) {
                float a8[8];
                float4 v0 = *(const float4*)&pr[kp * 32 + lk * 8];
                float4 v1 = *(const float4*)&pr[kp * 32 + lk * 8 + 4];
                a8[0]=v0.x; a8[1]=v0.y; a8[2]=v0.z; a8[3]=v0.w;
                a8[4]=v1.x; a8[5]=v1.y; a8[6]=v1.z; a8[7]=v1.w;
                bf16x8 ah, am, al;
                split3_8(a8, ah, am, al);
                acc = __builtin_amdgcn_mfma_f32_16x16x32_bf16(al, bh[kp], acc, 0, 0, 0);
                acc = __builtin_amdgcn_mfma_f32_16x16x32_bf16(ah, bl[kp], acc, 0, 0, 0);
                acc = __builtin_amdgcn_mfma_f32_16x16x32_bf16(am, bm[kp], acc, 0, 0, 0);
                acc = __builtin_amdgcn_mfma_f32_16x16x32_bf16(am, bh[kp], acc, 0, 0, 0);
                acc = __builtin_amdgcn_mfma_f32_16x16x32_bf16(ah, bm[kp], acc, 0, 0, 0);
                acc = __builtin_amdgcn_mfma_f32_16x16x32_bf16(ah, bh[kp], acc, 0, 0, 0);
            }
            // C: row=(lk*4+q) in tile -> j = jb + lk*4 + q ; col = g = lg
            #pragma unroll
            for (int q = 0; q < 4; ++q) {
                const float v = acc[q] + bias;
                wgl[ib][lg][jb + lk * 4 + q] = (v > 1e-6f) ? __logf(v) : LOG1E6;
            }
        }
        __syncthreads();
        // ---- phase S: 16 j per thread (identical to R8) ----
        {
            const float* ar = &aff[(((size_t)(c * GG + s_g)) * NT + (i0 + s_i)) * NT + j0 + s_h * 16];
            const float* wl = &wgl[s_i][s_g][s_h * 16];
            const float* il = &ios[s_i][s_h * 16];
            #pragma unroll
            for (int j4 = 0; j4 < 16; j4 += 4) {
                float4 a4 = *(const float4*)&ar[j4];
                float av[4] = {a4.x, a4.y, a4.z, a4.w};
                #pragma unroll
                for (int q = 0; q < 4; ++q) {
                    const float val = wl[j4 + q] + av[q] + il[j4 + q];
                    if (val > tv[0]) {
                        const int ix = j0 + s_h * 16 + j4 + q;
                        #pragma unroll
                        for (int sl = 0; sl < 10; ++sl) {
                            const bool up   = (sl < 9) ? (val > tv[sl + 1]) : false;
                            const bool here = (val > tv[sl]);
                            const float ntv = up ? tv[sl + 1] : (here ? val : tv[sl]);
                            const int   nti = up ? tidx[sl + 1] : (here ? ix : tidx[sl]);
                            tv[sl] = ntv; tidx[sl] = nti;
                        }
                    }
                }
            }
        }
        __syncthreads();
    }

    // ---- merge s_h=0/1 lists via LDS scratch (as R8) ----
    float* mv = &wgl[0][0][0];
    int*   mi = (int*)(mv + 1280);
    const int pair = t >> 1;
    if (s_h == 1) {
        #pragma unroll
        for (int q = 0; q < 10; ++q) { mv[pair * 10 + q] = tv[q]; mi[pair * 10 + q] = tidx[q]; }
    }
    __syncthreads();
    if (s_h == 0) {
        for (int q = 9; q >= 0; --q) {
            const float val = mv[pair * 10 + q];
            const int   ix  = mi[pair * 10 + q];
            if (val > tv[0]) {
                #pragma unroll
                for (int sl = 0; sl < 10; ++sl) {
                    const bool up   = (sl < 9) ? (val > tv[sl + 1]) : false;
                    const bool here = (val > tv[sl]);
                    const float ntv = up ? tv[sl + 1] : (here ? val : tv[sl]);
                    const int   nti = up ? tidx[sl + 1] : (here ? ix : tidx[sl]);
                    tv[sl] = ntv; tidx[sl] = nti;
                }
            }
        }
        const size_t base = ((((size_t)c * NT + (i0 + s_i)) * GG + s_g) * 4 + ch) * 10;
        #pragma unroll
        for (int q = 0; q < 10; ++q) { cv[base + q] = tv[q]; ci[base + q] = tidx[q]; }
    }
}

// ---------------------------------------------------------------------------
// K2b2: one 64-lane wave per (c,i,g) row; merge 4x10 ascending chunk lists
//       (scanned descending), softmax, coalesced V-gather.
// ---------------------------------------------------------------------------
__global__ __launch_bounds__(256) void k2b2_fin(
    const float* __restrict__ cv, const int* __restrict__ ci,
    const float* __restrict__ V, float* __restrict__ y)
{
    const int w    = (blockIdx.x << 2) + (threadIdx.x >> 6);
    const int lane = threadIdx.x & 63;
    const int c = w >> 14;
    const int i = (w >> 4) & (NT - 1);
    const int g = w & 15;

    float tv[10]; int tidx[10];
    #pragma unroll
    for (int q = 0; q < 10; ++q) { tv[q] = NEG_BIG; tidx[q] = 0; }

    const size_t base = (size_t)w * 40;
    for (int chn = 0; chn < 4; ++chn) {
        const float* cvp = &cv[base + chn * 10];
        const int*   cip = &ci[base + chn * 10];
        for (int q = 9; q >= 0; --q) {
            const float val = cvp[q];
            const int   ix  = cip[q];
            if (val > tv[0]) {
                #pragma unroll
                for (int sl = 0; sl < 10; ++sl) {
                    const bool up   = (sl < 9) ? (val > tv[sl + 1]) : false;
                    const bool here = (val > tv[sl]);
                    const float ntv = up ? tv[sl + 1] : (here ? val : tv[sl]);
                    const int   nti = up ? tidx[sl + 1] : (here ? ix : tidx[sl]);
                    tv[sl] = ntv; tidx[sl] = nti;
                }
            }
        }
    }
    const float m = tv[9];
    float wgt[10]; float sm = 0.f;
    #pragma unroll
    for (int q = 0; q < 10; ++q) { wgt[q] = __expf(tv[q] - m); sm += wgt[q]; }
    const float inv = 1.f / sm;
    float o = 0.f;
    #pragma unroll
    for (int q = 0; q < 10; ++q)
        o += (wgt[q] * inv) * V[((size_t)(c * NT + tidx[q])) * DD + g * 64 + lane];
    y[((size_t)i * CD + c) * DD + g * 64 + lane] = o;
}

extern "C" void kernel_launch(void* const* d_in, const int* in_sizes, int n_in,
                              void* d_out, int out_size, void* d_ws, size_t ws_size,
                              hipStream_t stream) {
    (void)in_sizes; (void)n_in; (void)out_size; (void)ws_size;
    const float* f_a = (const float*)d_in[0];
    const float* pe  = (const float*)d_in[1];
    const float* iou = (const float*)d_in[2];
    const float* WGw = (const float*)d_in[3];
    const float* WGb = (const float*)d_in[4];
    const float* WKw = (const float*)d_in[5];
    const float* WKb = (const float*)d_in[6];
    const float* WQw = (const float*)d_in[7];
    const float* WQb = (const float*)d_in[8];
    const float* Cw  = (const float*)d_in[9];
    const float* Cb  = (const float*)d_in[10];
    float* yout = (float*)d_out;

    // ws floats: Q [2^21] | K [2^21] | V [2^21] | aff [2^25]  (~159.4 MB)
    // cv overlays Q, ci overlays K (dead after k2a).
    float* ws  = (float*)d_ws;
    float* Q   = ws;
    float* Kp  = ws + (1u << 21);
    float* V   = ws + (2u << 21);
    float* aff = ws + (3u << 21);
    float* cv  = ws;
    int*   ci  = (int*)(ws + (1u << 21));

    k1_proj<<<dim3(16, 16, 3), 256, 0, stream>>>(f_a, WQw, WQb, WKw, WKb, Cw, Cb, Q, Kp, V);
    k2a_aff<<<dim3(16, 16, 32), 256, 0, stream>>>(Q, Kp, aff);
    k3_scan<<<dim3(4, 128, 2), 256, 0, stream>>>(pe, iou, WGw, WGb, aff, cv, ci);
    k2b2_fin<<<8192, 256, 0, stream>>>(cv, ci, V, yout);
}